// Round 2
// baseline (883.162 us; speedup 1.0000x reference)
//
#include <hip/hip_runtime.h>
#include <math.h>

#define NN 50000
#define NE 800000

// ---- workspace layout (float units) ----
#define OFF_U      0                         // U1[64x64] | U2[64x64]
#define OFF_WE2    8192                      // We@Wpre3: 3x64
#define OFF_BE2    8384                      // be@Wpre3: 64
#define OFF_B3     8448                      // bpost@Wih + bih: 192
#define OFF_SUML   8640                      // sum of log(deg_hist+1)
#define OFF_XW     8704                      // NN*384: [m | md2 | ms2 | gh_raw]
#define OFF_O1     (OFF_XW + NN*384)         // NN*256: [mean|min|max|std]
#define OFF_S2     (OFF_O1 + NN*256)         // NN: logd/avg_log
#define OFF_OUTPRE (OFF_S2 + NN)             // NN*64 (no bpost; folded into B3)
#define OFF_CNT    (OFF_OUTPRE + NN*64)      // NN int
#define OFF_OFFS   (OFF_CNT + NN)            // NN+1 int
#define OFF_CUR    (OFF_OFFS + NN + 1)       // NN int
#define OFF_ELIST  (OFF_CUR + NN)            // NE int

// ---- fold weights: U1,U2, We2, be2, bias3 ----
__global__ void k0_weights(const float* __restrict__ W, const float* __restrict__ Wpre,
                           const float* __restrict__ We, const float* __restrict__ be,
                           const float* __restrict__ bpost, const float* __restrict__ Wih,
                           const float* __restrict__ bih, float* __restrict__ ws)
{
    int idx = blockIdx.x * 256 + threadIdx.x;
    if (idx < 8192) {                       // U1 / U2
        int which = idx >> 12, k = (idx >> 6) & 63, j = idx & 63;
        const float* wp = Wpre + which * 64 * 64;
        float a = 0.f;
        for (int c = 0; c < 64; ++c) a += W[k*64 + c] * wp[c*64 + j];
        ws[OFF_U + idx] = a;
    } else if (idx < 8384) {                // We2
        int t = idx - 8192, k = t >> 6, j = t & 63;
        float a = 0.f;
        for (int c = 0; c < 64; ++c) a += We[k*64 + c] * Wpre[(128 + c)*64 + j];
        ws[OFF_WE2 + t] = a;
    } else if (idx < 8448) {                // be2
        int j = idx - 8384;
        float a = 0.f;
        for (int c = 0; c < 64; ++c) a += be[c] * Wpre[(128 + c)*64 + j];
        ws[OFF_BE2 + j] = a;
    } else if (idx < 8640) {                // bias3 = bpost@Wih + bih
        int j = idx - 8448;
        float a = bih[j];
        for (int k = 0; k < 64; ++k) a += bpost[k] * Wih[k*192 + j];
        ws[OFF_B3 + j] = a;
    }
}

__global__ void k_avglog(const float* __restrict__ dh, float* __restrict__ sum)
{
    int i = blockIdx.x * 256 + threadIdx.x;
    float v = (i < NN) ? logf(dh[i] + 1.f) : 0.f;
    #pragma unroll
    for (int m = 32; m >= 1; m >>= 1) v += __shfl_xor(v, m, 64);
    __shared__ float s[4];
    if ((threadIdx.x & 63) == 0) s[threadIdx.x >> 6] = v;
    __syncthreads();
    if (threadIdx.x == 0) atomicAdd(sum, s[0] + s[1] + s[2] + s[3]);
}

// ---- CSR build ----
__global__ void k_count(const int* __restrict__ dstA, int* __restrict__ cnt)
{
    int e = blockIdx.x * 256 + threadIdx.x;
    if (e < NE) atomicAdd(&cnt[dstA[e]], 1);
}

__global__ void k_scan(const int* __restrict__ cnt, int* __restrict__ offs,
                       int* __restrict__ cur)
{
    __shared__ int sh[1024];
    __shared__ int carry;
    int tid = threadIdx.x;
    if (tid == 0) carry = 0;
    __syncthreads();
    for (int base = 0; base < NN; base += 1024) {
        int i = base + tid;
        int v = (i < NN) ? cnt[i] : 0;
        sh[tid] = v; __syncthreads();
        int xacc = v;
        for (int o = 1; o < 1024; o <<= 1) {
            int t = (tid >= o) ? sh[tid - o] : 0;
            __syncthreads();
            xacc += t; sh[tid] = xacc;
            __syncthreads();
        }
        int excl = carry + xacc - v;
        if (i < NN) { offs[i] = excl; cur[i] = excl; }
        __syncthreads();
        if (tid == 1023) carry += xacc;
        __syncthreads();
    }
    if (tid == 0) offs[NN] = carry;
}

__global__ void k_scatter(const int* __restrict__ dstA, int* __restrict__ cur,
                          int* __restrict__ elist)
{
    int e = blockIdx.x * 256 + threadIdx.x;
    if (e < NE) { int p = atomicAdd(&cur[dstA[e]], 1); elist[p] = e; }
}

// ---- G1: xw = x @ [W | U1 | U2 | Whh]  (N x 384) ----
__global__ __launch_bounds__(384) void k_g1(const float* __restrict__ x,
    const float* __restrict__ W, const float* __restrict__ Whh,
    float* __restrict__ ws)
{
    int j = threadIdx.x;
    int n0 = blockIdx.x * 16;
    const float* base; int stride;
    if (j < 64)       { base = W + j;                        stride = 64;  }
    else if (j < 128) { base = ws + OFF_U + (j - 64);        stride = 64;  }
    else if (j < 192) { base = ws + OFF_U + 4096 + (j - 128); stride = 64; }
    else              { base = Whh + (j - 192);              stride = 192; }
    float wr[64];
    #pragma unroll
    for (int k = 0; k < 64; ++k) wr[k] = base[k * stride];
    float* __restrict__ out = ws + OFF_XW;
    for (int ni = 0; ni < 16; ++ni) {
        int n = n0 + ni;
        const float* __restrict__ xr = x + n * 64;   // uniform -> s_load
        float a0 = 0.f, a1 = 0.f;
        #pragma unroll
        for (int k = 0; k < 64; k += 2) { a0 += xr[k]*wr[k]; a1 += xr[k+1]*wr[k+1]; }
        out[(size_t)n * 384 + j] = a0 + a1;
    }
}

// ---- aggregation: one wave per node, lane = channel ----
__global__ __launch_bounds__(256) void k_agg(const int* __restrict__ srcA,
    const float* __restrict__ eattr, const float* __restrict__ bpre,
    float* __restrict__ ws)
{
    int lane = threadIdx.x & 63;
    int n = blockIdx.x * 4 + (threadIdx.x >> 6);   // NN/4 blocks exact
    const int* offs  = (const int*)(ws + OFF_OFFS);
    const int* elist = (const int*)(ws + OFF_ELIST);
    const float* __restrict__ xw = ws + OFF_XW;
    float we0 = ws[OFF_WE2 + lane], we1 = ws[OFF_WE2 + 64 + lane], we2 = ws[OFF_WE2 + 128 + lane];
    float be2l = ws[OFF_BE2 + lane], bprel = bpre[lane];
    float md2l = xw[(size_t)n * 384 + 64 + lane];
    int o0 = offs[n], o1e = offs[n + 1];
    float s = 0.f, ss = 0.f, mn = INFINITY, mx = -INFINITY;
    for (int i = o0; i < o1e; ++i) {
        int e = elist[i];
        int src = srcA[e];
        float a0 = eattr[e*4], a1 = eattr[e*4+1], a2 = eattr[e*4+2], ew = eattr[e*4+3];
        float ms2 = xw[(size_t)src * 384 + 128 + lane];
        float t = md2l + ms2 + a0*we0 + a1*we1 + a2*we2 + be2l;
        float h = ew * t + bprel;
        s += h; ss += h*h; mn = fminf(mn, h); mx = fmaxf(mx, h);
    }
    int deg = o1e - o0;
    float safe = (float)(deg > 0 ? deg : 1);
    float mean = s / safe;
    float var  = ss / safe - mean * mean;
    float stdv = sqrtf(fmaxf(var, 0.f) + 1e-5f);
    if (deg == 0) { mn = 0.f; mx = 0.f; }
    float* o1p = ws + OFF_O1 + (size_t)n * 256;
    o1p[lane] = mean; o1p[64+lane] = mn; o1p[128+lane] = mx; o1p[192+lane] = stdv;
    if (lane == 0) {
        float avg  = ws[OFF_SUML] * (1.f / NN);
        float logd = logf(safe + 1.f);
        ws[OFF_S2 + n] = logd / avg;
    }
}

// ---- G2: out_pre = [m|o1|s2*o1|o1] @ Wpost ----
// NOTE: o3 = o2*(avg/logd) = o1*s2*(1/s2) = o1 exactly -> fold Wp3 into Wp1.
__global__ __launch_bounds__(256) void k_g2(const float* __restrict__ Wpost,
                                            float* __restrict__ ws)
{
    const int lane = threadIdx.x & 63;
    const int w    = threadIdx.x >> 6;       // k-quarter owner (16 rows per chunk)
    const int n0   = blockIdx.x * 16;
    float acc1[16], acc2[16];
    #pragma unroll
    for (int i = 0; i < 16; ++i) { acc1[i]=0.f; acc2[i]=0.f; }
    const float* __restrict__ o1 = ws + OFF_O1;
    const float* __restrict__ xw = ws + OFF_XW;

    { // chunk: m (Wpost rows 0..63)
        float wr[16];
        #pragma unroll
        for (int r = 0; r < 16; ++r) wr[r] = Wpost[(w*16 + r)*64 + lane];
        #pragma unroll
        for (int ni = 0; ni < 16; ++ni) {
            const float* bp = xw + (size_t)(n0+ni)*384 + w*16;    // uniform -> s_load
            #pragma unroll
            for (int r = 0; r < 16; ++r) acc1[ni] += bp[r]*wr[r];
        }
    }
    #pragma unroll 1
    for (int c = 0; c < 4; ++c) {            // o1 @ (W1 + W3)  [o3 == o1]
        float wr[16];
        #pragma unroll
        for (int r = 0; r < 16; ++r)
            wr[r] = Wpost[((c+1)*64 + w*16 + r)*64 + lane]
                  + Wpost[((c+9)*64 + w*16 + r)*64 + lane];
        #pragma unroll
        for (int ni = 0; ni < 16; ++ni) {
            const float* bp = o1 + (size_t)(n0+ni)*256 + c*64 + w*16;
            #pragma unroll
            for (int r = 0; r < 16; ++r) acc1[ni] += bp[r]*wr[r];
        }
    }
    #pragma unroll 1
    for (int c = 0; c < 4; ++c) {            // o1 @ W2 (rows 320..575), scale s2 later
        float wr[16];
        #pragma unroll
        for (int r = 0; r < 16; ++r) wr[r] = Wpost[((c+5)*64 + w*16 + r)*64 + lane];
        #pragma unroll
        for (int ni = 0; ni < 16; ++ni) {
            const float* bp = o1 + (size_t)(n0+ni)*256 + c*64 + w*16;
            #pragma unroll
            for (int r = 0; r < 16; ++r) acc2[ni] += bp[r]*wr[r];
        }
    }

    __shared__ float part[4][16][64];        // 16 KiB
    #pragma unroll
    for (int ni = 0; ni < 16; ++ni) {
        float s2v = ws[OFF_S2 + n0 + ni];
        part[w][ni][lane] = acc1[ni] + s2v*acc2[ni];
    }
    __syncthreads();
    for (int idx = threadIdx.x; idx < 1024; idx += 256) {
        int ni = idx >> 6, jj = idx & 63;
        float v = part[0][ni][jj] + part[1][ni][jj] + part[2][ni][jj] + part[3][ni][jj];
        ws[OFF_OUTPRE + (size_t)(n0+ni)*64 + jj] = v;
    }
}

// ---- G3 + GRU fused: gi = out_pre@Wih (+bias3), then gates + output ----
__global__ __launch_bounds__(192) void k_g3gru(const float* __restrict__ x,
    const float* __restrict__ Wih, const float* __restrict__ bhh,
    float* __restrict__ ws, float* __restrict__ out)
{
    int j = threadIdx.x;                      // 0..191
    int n0 = blockIdx.x * 16;
    float wr[64];
    #pragma unroll
    for (int k = 0; k < 64; ++k) wr[k] = Wih[k*192 + j];
    __shared__ float gis[16][192];
    const float* __restrict__ op = ws + OFF_OUTPRE;
    float b3 = ws[OFF_B3 + j];
    for (int ni = 0; ni < 16; ++ni) {
        const float* __restrict__ r = op + (size_t)(n0+ni)*64;   // uniform -> s_load
        float a0 = b3, a1 = 0.f;
        #pragma unroll
        for (int k = 0; k < 64; k += 2) { a0 += r[k]*wr[k]; a1 += r[k+1]*wr[k+1]; }
        gis[ni][j] = a0 + a1;
    }
    __syncthreads();
    const float* __restrict__ xwp = ws + OFF_XW;
    for (int idx = threadIdx.x; idx < 1024; idx += 192) {
        int ni = idx >> 6, cc = idx & 63;
        int n = n0 + ni;
        float ir  = gis[ni][cc], iz = gis[ni][64+cc], inn = gis[ni][128+cc];
        const float* gh = xwp + (size_t)n*384 + 192;
        float hr = gh[cc]       + bhh[cc];
        float hz = gh[64 + cc]  + bhh[64 + cc];
        float hn = gh[128 + cc] + bhh[128 + cc];
        float rr = 1.f / (1.f + expf(-(ir + hr)));
        float zz = 1.f / (1.f + expf(-(iz + hz)));
        float nn = tanhf(inn + rr * hn);
        float xv = x[(size_t)n*64 + cc];
        out[(size_t)n*64 + cc] = (1.f - zz)*nn + zz*xv;
    }
}

extern "C" void kernel_launch(void* const* d_in, const int* in_sizes, int n_in,
                              void* d_out, int out_size, void* d_ws, size_t ws_size,
                              hipStream_t stream)
{
    const float* x     = (const float*)d_in[0];
    const float* eattr = (const float*)d_in[1];
    const float* dh    = (const float*)d_in[2];
    const float* W     = (const float*)d_in[3];
    const float* We    = (const float*)d_in[4];
    const float* be    = (const float*)d_in[5];
    const float* Wpre  = (const float*)d_in[6];
    const float* bpre  = (const float*)d_in[7];
    const float* Wpost = (const float*)d_in[8];
    const float* bpost = (const float*)d_in[9];
    const float* Wih   = (const float*)d_in[10];
    const float* bih   = (const float*)d_in[11];
    const float* Whh   = (const float*)d_in[12];
    const float* bhh   = (const float*)d_in[13];
    const int*   eidx  = (const int*)d_in[14];
    float* ws  = (float*)d_ws;
    float* out = (float*)d_out;
    const int* srcA = eidx;          // edge_index[0]
    const int* dstA = eidx + NE;     // edge_index[1]
    int* cnt   = (int*)(ws + OFF_CNT);
    int* offs  = (int*)(ws + OFF_OFFS);
    int* cur   = (int*)(ws + OFF_CUR);
    int* elist = (int*)(ws + OFF_ELIST);

    hipMemsetAsync(ws + OFF_SUML, 0, sizeof(float), stream);
    hipMemsetAsync(cnt, 0, NN * sizeof(int), stream);

    k0_weights<<<34, 256, 0, stream>>>(W, Wpre, We, be, bpost, Wih, bih, ws);
    k_avglog  <<<(NN + 255)/256, 256, 0, stream>>>(dh, ws + OFF_SUML);
    k_count   <<<NE/256, 256, 0, stream>>>(dstA, cnt);
    k_scan    <<<1, 1024, 0, stream>>>(cnt, offs, cur);
    k_scatter <<<NE/256, 256, 0, stream>>>(dstA, cur, elist);
    k_g1      <<<NN/16, 384, 0, stream>>>(x, W, Whh, ws);
    k_agg     <<<NN/4, 256, 0, stream>>>(srcA, eattr, bpre, ws);
    k_g2      <<<NN/16, 256, 0, stream>>>(Wpost, ws);
    k_g3gru   <<<NN/16, 192, 0, stream>>>(x, Wih, bhh, ws, out);
}

// Round 3
// 476.481 us; speedup vs baseline: 1.8535x; 1.8535x over previous
//
#include <hip/hip_runtime.h>
#include <math.h>

#define NN  50000
#define NNP 50048
#define NE  800000

// ---- workspace byte offsets ----
#define B_BG1   0u          // g1 B frags: 24 tiles x 2 ksteps x 64 lanes x 8 bf16 = 49152 B
#define B_BG2   49152u      // g2 B frags: 4 x 18 x 512 bf16 = 73728 B
#define B_BG3   122880u     // g3 B frags: 12 x 2 x 512 bf16 = 24576 B
#define B_WE2   147456u     // 3x64 f32
#define B_BE2   148224u     // 64 f32
#define B_B3    148480u     // 192 f32 (bpost@Wih + bih)
#define B_SUML  149248u     // 1 f32
#define B_XB    149504u     // x bf16: NNP*64
#define B_NF    6555648u    // [md2|ms2] bf16: NNP*128
#define B_GH    19367936u   // gh bf16: NNP*192
#define B_A2    38586368u   // [m|o1|s2*o1] bf16: NNP*576
#define B_A3    96241664u   // out_pre bf16: NNP*64
#define B_CNT   102647808u  // NN int
#define B_OFFS  102847808u  // NN+1 int
#define B_CUR   103047936u  // NN int
#define B_EL2   103247936u  // NE int2 (e, src)
// end ~109.7 MB (prior round used 146 MB OK)

typedef __attribute__((ext_vector_type(8))) short s8v;
typedef __attribute__((ext_vector_type(4))) float f4v;

__device__ inline short f2b(float f){
    union { float f; unsigned u; } v; v.f = f;
    unsigned r = v.u + 0x7fffu + ((v.u >> 16) & 1u);
    return (short)(r >> 16);
}
__device__ inline float b2f(short b){
    union { unsigned u; float f; } v; v.u = ((unsigned)(unsigned short)b) << 16;
    return v.f;
}

// ---- k0: fold + pack all B matrices into MFMA fragment order (bf16) ----
// B-frag layout per (tile ts): lane l, j=0..7 -> B[k = s*32 + (l>>4)*8 + j][n = t*16 + (l&15)]
__global__ void k0_weights(const float* __restrict__ W, const float* __restrict__ Wpre,
                           const float* __restrict__ We, const float* __restrict__ be,
                           const float* __restrict__ bpost, const float* __restrict__ Wpost,
                           const float* __restrict__ Wih, const float* __restrict__ bih,
                           const float* __restrict__ Whh, unsigned char* __restrict__ wsb)
{
    int idx = blockIdx.x * 256 + threadIdx.x;
    if (idx < 3072) {                       // bg1: B = [W | U1 | U2 | Whh] (64 x 384)
        short* dst = (short*)(wsb + B_BG1);
        int lane = idx & 63, ts = idx >> 6;          // ts = t*2+s, t=0..23
        int t = ts >> 1, s = ts & 1;
        int quad = lane >> 4, l15 = lane & 15, n = t*16 + l15;
        for (int j = 0; j < 8; ++j) {
            int k = s*32 + quad*8 + j;
            float v;
            if (n < 64)       v = W[k*64 + n];
            else if (n < 128) { v = 0.f; for (int c = 0; c < 64; ++c) v += W[k*64+c]*Wpre[c*64 + (n-64)]; }
            else if (n < 192) { v = 0.f; for (int c = 0; c < 64; ++c) v += W[k*64+c]*Wpre[4096 + c*64 + (n-128)]; }
            else              v = Whh[k*192 + (n-192)];
            dst[((size_t)ts*64 + lane)*8 + j] = f2b(v);
        }
    } else if (idx < 3072 + 4608) {         // bg2: B = [Wp_m; W1+W3; W2] (576 x 64)
        int id = idx - 3072;
        short* dst = (short*)(wsb + B_BG2);
        int lane = id & 63, ts = id >> 6;            // ts = t*18+s, t=0..3, s=0..17
        int quad = lane >> 4, l15 = lane & 15;
        int t = ts / 18, s = ts % 18;
        int n = t*16 + l15;
        for (int j = 0; j < 8; ++j) {
            int k = s*32 + quad*8 + j;
            float v;
            if (k < 64)       v = Wpost[k*64 + n];
            else if (k < 320) v = Wpost[k*64 + n] + Wpost[(k+512)*64 + n];  // o3==o1 fold
            else              v = Wpost[k*64 + n];
            dst[((size_t)ts*64 + lane)*8 + j] = f2b(v);
        }
    } else if (idx < 9216) {                // bg3: B = Wih (64 x 192)
        int id = idx - 7680;
        short* dst = (short*)(wsb + B_BG3);
        int lane = id & 63, ts = id >> 6;            // ts = t*2+s, t=0..11
        int t = ts >> 1, s = ts & 1;
        int quad = lane >> 4, l15 = lane & 15, n = t*16 + l15;
        for (int j = 0; j < 8; ++j) {
            int k = s*32 + quad*8 + j;
            dst[((size_t)ts*64 + lane)*8 + j] = f2b(Wih[k*192 + n]);
        }
    } else if (idx < 9408) {                // We2 = We @ Wpre3 (3 x 64)
        int t2 = idx - 9216; int kk = t2 >> 6, j = t2 & 63;
        float v = 0.f;
        for (int c = 0; c < 64; ++c) v += We[kk*64 + c] * Wpre[(128+c)*64 + j];
        ((float*)(wsb + B_WE2))[t2] = v;
    } else if (idx < 9472) {                // be2 = be @ Wpre3
        int j = idx - 9408;
        float v = 0.f;
        for (int c = 0; c < 64; ++c) v += be[c] * Wpre[(128+c)*64 + j];
        ((float*)(wsb + B_BE2))[j] = v;
    } else if (idx < 9664) {                // b3 = bpost@Wih + bih
        int j = idx - 9472;
        float v = bih[j];
        for (int k = 0; k < 64; ++k) v += bpost[k] * Wih[k*192 + j];
        ((float*)(wsb + B_B3))[j] = v;
    }
}

__global__ void k_avglog(const float* __restrict__ dh, float* __restrict__ sum)
{
    int i = blockIdx.x * 256 + threadIdx.x;
    float v = (i < NN) ? logf(dh[i] + 1.f) : 0.f;
    #pragma unroll
    for (int m = 32; m >= 1; m >>= 1) v += __shfl_xor(v, m, 64);
    __shared__ float s[4];
    if ((threadIdx.x & 63) == 0) s[threadIdx.x >> 6] = v;
    __syncthreads();
    if (threadIdx.x == 0) atomicAdd(sum, s[0] + s[1] + s[2] + s[3]);
}

// ---- x -> bf16 ----
__global__ void k_xcast(const float* __restrict__ x, unsigned char* __restrict__ wsb)
{
    int i = blockIdx.x * 256 + threadIdx.x;
    if ((size_t)i * 8 >= (size_t)NN * 64) return;
    const float4* xp = (const float4*)(x + (size_t)i * 8);
    float4 p0 = xp[0], p1 = xp[1];
    s8v o;
    o[0]=f2b(p0.x); o[1]=f2b(p0.y); o[2]=f2b(p0.z); o[3]=f2b(p0.w);
    o[4]=f2b(p1.x); o[5]=f2b(p1.y); o[6]=f2b(p1.z); o[7]=f2b(p1.w);
    *(s8v*)((short*)(wsb + B_XB) + (size_t)i * 8) = o;
}

// ---- CSR build ----
__global__ void k_count(const int* __restrict__ dstA, int* __restrict__ cnt)
{
    int e = blockIdx.x * 256 + threadIdx.x;
    if (e < NE) atomicAdd(&cnt[dstA[e]], 1);
}

__global__ void k_scan(const int* __restrict__ cnt, int* __restrict__ offs,
                       int* __restrict__ cur)
{
    __shared__ int sh[1024];
    const int CH = 49;                       // 1024*49 = 50176 >= NN
    int t = threadIdx.x;
    int lo = t * CH, hi = lo + CH;
    if (lo > NN) lo = NN;
    if (hi > NN) hi = NN;
    int s = 0;
    for (int i = lo; i < hi; ++i) s += cnt[i];
    sh[t] = s; __syncthreads();
    for (int o = 1; o < 1024; o <<= 1) {
        int v = (t >= o) ? sh[t - o] : 0;
        __syncthreads();
        sh[t] += v;
        __syncthreads();
    }
    int run = sh[t] - s;                     // exclusive base
    for (int i = lo; i < hi; ++i) { offs[i] = run; cur[i] = run; run += cnt[i]; }
    if (t == 1023) offs[NN] = run;
}

__global__ void k_scatter(const int* __restrict__ srcA, const int* __restrict__ dstA,
                          int* __restrict__ cur, int2* __restrict__ el2)
{
    int e = blockIdx.x * 256 + threadIdx.x;
    if (e < NE) {
        int p = atomicAdd(&cur[dstA[e]], 1);
        el2[p] = make_int2(e, srcA[e]);      // kill the elist->src dependent load
    }
}

// ---- G1 (MFMA): xw = x @ [W|U1|U2|Whh], epilogue -> a2(m), nf(md2|ms2), gh ----
__global__ __launch_bounds__(256) void k_g1(unsigned char* __restrict__ wsb)
{
    const short* xb = (const short*)(wsb + B_XB);
    const short* bf = (const short*)(wsb + B_BG1);
    short* a2 = (short*)(wsb + B_A2);
    short* nf = (short*)(wsb + B_NF);
    short* gh = (short*)(wsb + B_GH);
    int w = threadIdx.x >> 6, lane = threadIdx.x & 63;
    int quad = lane >> 4, l15 = lane & 15;
    int R0 = blockIdx.x * 64 + w * 16;
    const short* arow = xb + (size_t)(R0 + l15) * 64 + quad * 8;
    s8v a0 = *(const s8v*)(arow);
    s8v a1 = *(const s8v*)(arow + 32);
    f4v acc[24];
    #pragma unroll
    for (int t = 0; t < 24; ++t) acc[t] = (f4v){0.f,0.f,0.f,0.f};
    #pragma unroll
    for (int t = 0; t < 24; ++t) {
        s8v b0 = *(const s8v*)(bf + ((size_t)(t*2+0)*64 + lane)*8);
        s8v b1 = *(const s8v*)(bf + ((size_t)(t*2+1)*64 + lane)*8);
        acc[t] = __builtin_amdgcn_mfma_f32_16x16x32_bf16(a0, b0, acc[t], 0, 0, 0);
        acc[t] = __builtin_amdgcn_mfma_f32_16x16x32_bf16(a1, b1, acc[t], 0, 0, 0);
    }
    #pragma unroll
    for (int t = 0; t < 24; ++t) {
        #pragma unroll
        for (int r = 0; r < 4; ++r) {
            int row = R0 + quad*4 + r;
            if (row >= NN) continue;
            short v = f2b(acc[t][r]);
            if (t < 4)       a2[(size_t)row*576 + t*16 + l15] = v;
            else if (t < 12) nf[(size_t)row*128 + (t-4)*16 + l15] = v;
            else             gh[(size_t)row*192 + (t-12)*16 + l15] = v;
        }
    }
}

// ---- aggregation: one wave per node, lane = channel; writes o1 & s2*o1 bf16 ----
__global__ __launch_bounds__(256) void k_agg(const float* __restrict__ eattr,
    const float* __restrict__ bpre, unsigned char* __restrict__ wsb)
{
    int lane = threadIdx.x & 63;
    int n = blockIdx.x * 4 + (threadIdx.x >> 6);
    const int* offs = (const int*)(wsb + B_OFFS);
    const int2* el2 = (const int2*)(wsb + B_EL2);
    const short* nf = (const short*)(wsb + B_NF);
    const float* we2p = (const float*)(wsb + B_WE2);
    float we0 = we2p[lane], we1 = we2p[64 + lane], we2v = we2p[128 + lane];
    float be2l = ((const float*)(wsb + B_BE2))[lane];
    float bprel = bpre[lane];
    float md2l = b2f(nf[(size_t)n * 128 + lane]);
    int o0 = offs[n], o1e = offs[n + 1];
    const float4* e4 = (const float4*)eattr;
    float s = 0.f, ss = 0.f, mn = INFINITY, mx = -INFINITY;
    for (int i = o0; i < o1e; ++i) {
        int2 es = el2[i];
        float4 ea = e4[es.x];
        float ms2 = b2f(nf[(size_t)es.y * 128 + 64 + lane]);
        float t = md2l + ms2 + ea.x*we0 + ea.y*we1 + ea.z*we2v + be2l;
        float h = ea.w * t + bprel;
        s += h; ss += h*h; mn = fminf(mn, h); mx = fmaxf(mx, h);
    }
    int deg = o1e - o0;
    float safe = (float)(deg > 0 ? deg : 1);
    float mean = s / safe;
    float var  = ss / safe - mean * mean;
    float stdv = sqrtf(fmaxf(var, 0.f) + 1e-5f);
    if (deg == 0) { mn = 0.f; mx = 0.f; }
    float avg  = ((const float*)(wsb + B_SUML))[0] * (1.f / NN);
    float s2   = logf(safe + 1.f) / avg;           // o2 = s2*o1; o3 = o1 (s2*s3==1)
    short* a2 = (short*)(wsb + B_A2) + (size_t)n * 576;
    a2[ 64 + lane] = f2b(mean);    a2[128 + lane] = f2b(mn);
    a2[192 + lane] = f2b(mx);      a2[256 + lane] = f2b(stdv);
    a2[320 + lane] = f2b(s2*mean); a2[384 + lane] = f2b(s2*mn);
    a2[448 + lane] = f2b(s2*mx);   a2[512 + lane] = f2b(s2*stdv);
}

// ---- G2 (MFMA): out_pre = a2 @ [Wp_m; W1+W3; W2]  (K=576, N=64) ----
__global__ __launch_bounds__(256) void k_g2(unsigned char* __restrict__ wsb)
{
    const short* a2 = (const short*)(wsb + B_A2);
    const short* bf = (const short*)(wsb + B_BG2);
    short* a3 = (short*)(wsb + B_A3);
    int w = threadIdx.x >> 6, lane = threadIdx.x & 63;
    int quad = lane >> 4, l15 = lane & 15;
    int R0 = blockIdx.x * 64 + w * 16;
    const short* arow = a2 + (size_t)(R0 + l15) * 576 + quad * 8;
    f4v acc[4];
    #pragma unroll
    for (int t = 0; t < 4; ++t) acc[t] = (f4v){0.f,0.f,0.f,0.f};
    #pragma unroll 3
    for (int sK = 0; sK < 18; ++sK) {
        s8v a = *(const s8v*)(arow + sK * 32);
        #pragma unroll
        for (int t = 0; t < 4; ++t) {
            s8v b = *(const s8v*)(bf + ((size_t)(t*18 + sK)*64 + lane)*8);
            acc[t] = __builtin_amdgcn_mfma_f32_16x16x32_bf16(a, b, acc[t], 0, 0, 0);
        }
    }
    #pragma unroll
    for (int t = 0; t < 4; ++t)
        #pragma unroll
        for (int r = 0; r < 4; ++r) {
            int row = R0 + quad*4 + r;
            if (row < NN) a3[(size_t)row*64 + t*16 + l15] = f2b(acc[t][r]);
        }
}

// ---- G3 (MFMA) + GRU epilogue ----
__global__ __launch_bounds__(256) void k_g3gru(const float* __restrict__ x,
    const float* __restrict__ bhh, unsigned char* __restrict__ wsb,
    float* __restrict__ out)
{
    const short* a3 = (const short*)(wsb + B_A3);
    const short* bf = (const short*)(wsb + B_BG3);
    const short* gh = (const short*)(wsb + B_GH);
    const float* b3 = (const float*)(wsb + B_B3);
    int w = threadIdx.x >> 6, lane = threadIdx.x & 63;
    int quad = lane >> 4, l15 = lane & 15;
    int R0 = blockIdx.x * 64 + w * 16;
    const short* arow = a3 + (size_t)(R0 + l15) * 64 + quad * 8;
    s8v a0 = *(const s8v*)(arow);
    s8v a1 = *(const s8v*)(arow + 32);
    f4v acc[12];
    #pragma unroll
    for (int t = 0; t < 12; ++t) acc[t] = (f4v){0.f,0.f,0.f,0.f};
    #pragma unroll
    for (int t = 0; t < 12; ++t) {
        s8v b0 = *(const s8v*)(bf + ((size_t)(t*2+0)*64 + lane)*8);
        s8v b1 = *(const s8v*)(bf + ((size_t)(t*2+1)*64 + lane)*8);
        acc[t] = __builtin_amdgcn_mfma_f32_16x16x32_bf16(a0, b0, acc[t], 0, 0, 0);
        acc[t] = __builtin_amdgcn_mfma_f32_16x16x32_bf16(a1, b1, acc[t], 0, 0, 0);
    }
    #pragma unroll
    for (int t = 0; t < 4; ++t) {
        #pragma unroll
        for (int r = 0; r < 4; ++r) {
            int row = R0 + quad*4 + r;
            if (row >= NN) continue;
            int c = t*16 + l15;
            float ir  = acc[t][r]   + b3[c];
            float iz  = acc[t+4][r] + b3[64 + c];
            float inn = acc[t+8][r] + b3[128 + c];
            const short* g = gh + (size_t)row * 192;
            float hr = b2f(g[c])       + bhh[c];
            float hz = b2f(g[64 + c])  + bhh[64 + c];
            float hn = b2f(g[128 + c]) + bhh[128 + c];
            float rr = 1.f / (1.f + expf(-(ir + hr)));
            float zz = 1.f / (1.f + expf(-(iz + hz)));
            float nn = tanhf(inn + rr * hn);
            out[(size_t)row*64 + c] = (1.f - zz)*nn + zz*x[(size_t)row*64 + c];
        }
    }
}

extern "C" void kernel_launch(void* const* d_in, const int* in_sizes, int n_in,
                              void* d_out, int out_size, void* d_ws, size_t ws_size,
                              hipStream_t stream)
{
    const float* x     = (const float*)d_in[0];
    const float* eattr = (const float*)d_in[1];
    const float* dh    = (const float*)d_in[2];
    const float* W     = (const float*)d_in[3];
    const float* We    = (const float*)d_in[4];
    const float* be    = (const float*)d_in[5];
    const float* Wpre  = (const float*)d_in[6];
    const float* bpre  = (const float*)d_in[7];
    const float* Wpost = (const float*)d_in[8];
    const float* bpost = (const float*)d_in[9];
    const float* Wih   = (const float*)d_in[10];
    const float* bih   = (const float*)d_in[11];
    const float* Whh   = (const float*)d_in[12];
    const float* bhh   = (const float*)d_in[13];
    const int*   eidx  = (const int*)d_in[14];
    unsigned char* wsb = (unsigned char*)d_ws;
    float* out = (float*)d_out;
    const int* srcA = eidx;
    const int* dstA = eidx + NE;
    int* cnt  = (int*)(wsb + B_CNT);
    int* offs = (int*)(wsb + B_OFFS);
    int* cur  = (int*)(wsb + B_CUR);
    int2* el2 = (int2*)(wsb + B_EL2);

    hipMemsetAsync(wsb + B_SUML, 0, 4, stream);
    hipMemsetAsync(cnt, 0, NN * sizeof(int), stream);

    k0_weights<<<38, 256, 0, stream>>>(W, Wpre, We, be, bpost, Wpost, Wih, bih, Whh, wsb);
    k_avglog  <<<(NN + 255)/256, 256, 0, stream>>>(dh, (float*)(wsb + B_SUML));
    k_count   <<<NE/256, 256, 0, stream>>>(dstA, cnt);
    k_scan    <<<1, 1024, 0, stream>>>(cnt, offs, cur);
    k_scatter <<<NE/256, 256, 0, stream>>>(srcA, dstA, cur, el2);
    k_xcast   <<<1563, 256, 0, stream>>>(x, wsb);
    k_g1      <<<NNP/64, 256, 0, stream>>>(wsb);
    k_agg     <<<NN/4, 256, 0, stream>>>(eattr, bpre, wsb);
    k_g2      <<<NNP/64, 256, 0, stream>>>(wsb);
    k_g3gru   <<<NNP/64, 256, 0, stream>>>(x, bhh, wsb, out);
}

// Round 4
// 367.912 us; speedup vs baseline: 2.4005x; 1.2951x over previous
//
#include <hip/hip_runtime.h>
#include <math.h>

#define NN  50000
#define NNP 50048
#define NE  800000

// ---- workspace byte offsets ----
#define B_BG1   0u          // g1 B frags: 24 tiles x 2 ksteps x 64 lanes x 8 bf16 = 49152 B
#define B_BG2   49152u      // g2 B frags: 4 x 18 x 512 bf16 = 73728 B
#define B_BG3   122880u     // g3 B frags: 12 x 2 x 512 bf16 = 24576 B
#define B_WE2   147456u     // 3x64 f32
#define B_BE2   148224u     // 64 f32
#define B_B3    148480u     // 192 f32 (bpost@Wih + bih)
#define B_SUML  149248u     // 1 f32
#define B_XB    149504u     // x bf16: NNP*64
#define B_NF    6555648u    // [md2|ms2] bf16: NNP*128
#define B_GH    19367936u   // gh bf16: NNP*192
#define B_A2    38586368u   // [m|o1|s2*o1] bf16: NNP*576
#define B_A3    96241664u   // out_pre bf16: NNP*64
#define B_CNT   102647808u  // NN int
#define B_OFFS  102847808u  // NN+1 int
#define B_CUR   103047936u  // NN int (also holds per-block local scans mid-pipeline)
#define B_EL2   103247936u  // NE int2 (e, src)
#define B_PART  109647936u  // 196 int block partials
// end ~109.65 MB

#define SCAN_B  196         // 196*256 = 50176 >= NN

typedef __attribute__((ext_vector_type(8))) short s8v;
typedef __attribute__((ext_vector_type(4))) float f4v;

__device__ inline short f2b(float f){
    union { float f; unsigned u; } v; v.f = f;
    unsigned r = v.u + 0x7fffu + ((v.u >> 16) & 1u);
    return (short)(r >> 16);
}
__device__ inline float b2f(short b){
    union { unsigned u; float f; } v; v.u = ((unsigned)(unsigned short)b) << 16;
    return v.f;
}

// ---- k0: fold + pack all B matrices into MFMA fragment order (bf16) ----
__global__ void k0_weights(const float* __restrict__ W, const float* __restrict__ Wpre,
                           const float* __restrict__ We, const float* __restrict__ be,
                           const float* __restrict__ bpost, const float* __restrict__ Wpost,
                           const float* __restrict__ Wih, const float* __restrict__ bih,
                           const float* __restrict__ Whh, unsigned char* __restrict__ wsb)
{
    int idx = blockIdx.x * 256 + threadIdx.x;
    if (idx < 3072) {                       // bg1: B = [W | U1 | U2 | Whh] (64 x 384)
        short* dst = (short*)(wsb + B_BG1);
        int lane = idx & 63, ts = idx >> 6;          // ts = t*2+s, t=0..23
        int t = ts >> 1, s = ts & 1;
        int quad = lane >> 4, l15 = lane & 15, n = t*16 + l15;
        for (int j = 0; j < 8; ++j) {
            int k = s*32 + quad*8 + j;
            float v;
            if (n < 64)       v = W[k*64 + n];
            else if (n < 128) { v = 0.f; for (int c = 0; c < 64; ++c) v += W[k*64+c]*Wpre[c*64 + (n-64)]; }
            else if (n < 192) { v = 0.f; for (int c = 0; c < 64; ++c) v += W[k*64+c]*Wpre[4096 + c*64 + (n-128)]; }
            else              v = Whh[k*192 + (n-192)];
            dst[((size_t)ts*64 + lane)*8 + j] = f2b(v);
        }
    } else if (idx < 3072 + 4608) {         // bg2: B = [Wp_m; W1+W3; W2] (576 x 64)
        int id = idx - 3072;
        short* dst = (short*)(wsb + B_BG2);
        int lane = id & 63, ts = id >> 6;            // ts = t*18+s, t=0..3, s=0..17
        int quad = lane >> 4, l15 = lane & 15;
        int t = ts / 18, s = ts % 18;
        int n = t*16 + l15;
        for (int j = 0; j < 8; ++j) {
            int k = s*32 + quad*8 + j;
            float v;
            if (k < 64)       v = Wpost[k*64 + n];
            else if (k < 320) v = Wpost[k*64 + n] + Wpost[(k+512)*64 + n];  // o3==o1 fold
            else              v = Wpost[k*64 + n];
            dst[((size_t)ts*64 + lane)*8 + j] = f2b(v);
        }
    } else if (idx < 9216) {                // bg3: B = Wih (64 x 192)
        int id = idx - 7680;
        short* dst = (short*)(wsb + B_BG3);
        int lane = id & 63, ts = id >> 6;            // ts = t*2+s, t=0..11
        int t = ts >> 1, s = ts & 1;
        int quad = lane >> 4, l15 = lane & 15, n = t*16 + l15;
        for (int j = 0; j < 8; ++j) {
            int k = s*32 + quad*8 + j;
            dst[((size_t)ts*64 + lane)*8 + j] = f2b(Wih[k*192 + n]);
        }
    } else if (idx < 9408) {                // We2 = We @ Wpre3 (3 x 64)
        int t2 = idx - 9216; int kk = t2 >> 6, j = t2 & 63;
        float v = 0.f;
        for (int c = 0; c < 64; ++c) v += We[kk*64 + c] * Wpre[(128+c)*64 + j];
        ((float*)(wsb + B_WE2))[t2] = v;
    } else if (idx < 9472) {                // be2 = be @ Wpre3
        int j = idx - 9408;
        float v = 0.f;
        for (int c = 0; c < 64; ++c) v += be[c] * Wpre[(128+c)*64 + j];
        ((float*)(wsb + B_BE2))[j] = v;
    } else if (idx < 9664) {                // b3 = bpost@Wih + bih
        int j = idx - 9472;
        float v = bih[j];
        for (int k = 0; k < 64; ++k) v += bpost[k] * Wih[k*192 + j];
        ((float*)(wsb + B_B3))[j] = v;
    }
}

__global__ void k_avglog(const float* __restrict__ dh, float* __restrict__ sum)
{
    int i = blockIdx.x * 256 + threadIdx.x;
    float v = (i < NN) ? logf(dh[i] + 1.f) : 0.f;
    #pragma unroll
    for (int m = 32; m >= 1; m >>= 1) v += __shfl_xor(v, m, 64);
    __shared__ float s[4];
    if ((threadIdx.x & 63) == 0) s[threadIdx.x >> 6] = v;
    __syncthreads();
    if (threadIdx.x == 0) atomicAdd(sum, s[0] + s[1] + s[2] + s[3]);
}

// ---- x -> bf16 ----
__global__ void k_xcast(const float* __restrict__ x, unsigned char* __restrict__ wsb)
{
    int i = blockIdx.x * 256 + threadIdx.x;
    if ((size_t)i * 8 >= (size_t)NN * 64) return;
    const float4* xp = (const float4*)(x + (size_t)i * 8);
    float4 p0 = xp[0], p1 = xp[1];
    s8v o;
    o[0]=f2b(p0.x); o[1]=f2b(p0.y); o[2]=f2b(p0.z); o[3]=f2b(p0.w);
    o[4]=f2b(p1.x); o[5]=f2b(p1.y); o[6]=f2b(p1.z); o[7]=f2b(p1.w);
    *(s8v*)((short*)(wsb + B_XB) + (size_t)i * 8) = o;
}

// ---- CSR build ----
__global__ void k_count(const int* __restrict__ dstA, int* __restrict__ cnt)
{
    int e = blockIdx.x * 256 + threadIdx.x;
    if (e < NE) atomicAdd(&cnt[dstA[e]], 1);
}

// 3-phase scan: A) per-block local scan + partial, B) scan partials, C) add base
__global__ __launch_bounds__(256) void k_scanA(const int* __restrict__ cnt,
    int* __restrict__ loc, int* __restrict__ part)
{
    __shared__ int sh[256];
    int t = threadIdx.x, i = blockIdx.x * 256 + t;
    int v = (i < NN) ? cnt[i] : 0;
    sh[t] = v; __syncthreads();
    #pragma unroll
    for (int o = 1; o < 256; o <<= 1) {
        int u = (t >= o) ? sh[t - o] : 0;
        __syncthreads();
        sh[t] += u;
        __syncthreads();
    }
    if (i < NN) loc[i] = sh[t] - v;          // block-local exclusive
    if (t == 255) part[blockIdx.x] = sh[255];
}

__global__ __launch_bounds__(256) void k_scanB(int* __restrict__ part,
    int* __restrict__ offs)
{
    __shared__ int sh[256];
    int t = threadIdx.x;
    int v = (t < SCAN_B) ? part[t] : 0;
    sh[t] = v; __syncthreads();
    #pragma unroll
    for (int o = 1; o < 256; o <<= 1) {
        int u = (t >= o) ? sh[t - o] : 0;
        __syncthreads();
        sh[t] += u;
        __syncthreads();
    }
    if (t < SCAN_B) part[t] = sh[t] - v;     // exclusive base per block
    if (t == 255) offs[NN] = sh[255];        // total edge count (= NE)
}

__global__ __launch_bounds__(256) void k_scanC(const int* __restrict__ part,
    int* __restrict__ loc, int* __restrict__ offs, int* __restrict__ cur)
{
    int i = blockIdx.x * 256 + threadIdx.x;
    if (i < NN) {
        int v = loc[i] + part[blockIdx.x];
        offs[i] = v; cur[i] = v;
    }
}

__global__ void k_scatter(const int* __restrict__ srcA, const int* __restrict__ dstA,
                          int* __restrict__ cur, int2* __restrict__ el2)
{
    int e = blockIdx.x * 256 + threadIdx.x;
    if (e < NE) {
        int p = atomicAdd(&cur[dstA[e]], 1);
        el2[p] = make_int2(e, srcA[e]);
    }
}

// ---- G1 (MFMA): xw = x @ [W|U1|U2|Whh], epilogue -> a2(m), nf(md2|ms2), gh ----
__global__ __launch_bounds__(256) void k_g1(unsigned char* __restrict__ wsb)
{
    const short* xb = (const short*)(wsb + B_XB);
    const short* bf = (const short*)(wsb + B_BG1);
    short* a2 = (short*)(wsb + B_A2);
    short* nf = (short*)(wsb + B_NF);
    short* gh = (short*)(wsb + B_GH);
    int w = threadIdx.x >> 6, lane = threadIdx.x & 63;
    int quad = lane >> 4, l15 = lane & 15;
    int R0 = blockIdx.x * 64 + w * 16;
    const short* arow = xb + (size_t)(R0 + l15) * 64 + quad * 8;
    s8v a0 = *(const s8v*)(arow);
    s8v a1 = *(const s8v*)(arow + 32);
    f4v acc[24];
    #pragma unroll
    for (int t = 0; t < 24; ++t) acc[t] = (f4v){0.f,0.f,0.f,0.f};
    #pragma unroll
    for (int t = 0; t < 24; ++t) {
        s8v b0 = *(const s8v*)(bf + ((size_t)(t*2+0)*64 + lane)*8);
        s8v b1 = *(const s8v*)(bf + ((size_t)(t*2+1)*64 + lane)*8);
        acc[t] = __builtin_amdgcn_mfma_f32_16x16x32_bf16(a0, b0, acc[t], 0, 0, 0);
        acc[t] = __builtin_amdgcn_mfma_f32_16x16x32_bf16(a1, b1, acc[t], 0, 0, 0);
    }
    #pragma unroll
    for (int t = 0; t < 24; ++t) {
        #pragma unroll
        for (int r = 0; r < 4; ++r) {
            int row = R0 + quad*4 + r;
            if (row >= NN) continue;
            short v = f2b(acc[t][r]);
            if (t < 4)       a2[(size_t)row*576 + t*16 + l15] = v;
            else if (t < 12) nf[(size_t)row*128 + (t-4)*16 + l15] = v;
            else             gh[(size_t)row*192 + (t-12)*16 + l15] = v;
        }
    }
}

// ---- aggregation: one wave per node, lane = channel; writes o1 & s2*o1 bf16 ----
__global__ __launch_bounds__(256) void k_agg(const float* __restrict__ eattr,
    const float* __restrict__ bpre, unsigned char* __restrict__ wsb)
{
    int lane = threadIdx.x & 63;
    int n = blockIdx.x * 4 + (threadIdx.x >> 6);
    const int* offs = (const int*)(wsb + B_OFFS);
    const int2* el2 = (const int2*)(wsb + B_EL2);
    const short* nf = (const short*)(wsb + B_NF);
    const float* we2p = (const float*)(wsb + B_WE2);
    float we0 = we2p[lane], we1 = we2p[64 + lane], we2v = we2p[128 + lane];
    float be2l = ((const float*)(wsb + B_BE2))[lane];
    float bprel = bpre[lane];
    float md2l = b2f(nf[(size_t)n * 128 + lane]);
    int o0 = offs[n], o1e = offs[n + 1];
    const float4* e4 = (const float4*)eattr;
    float s = 0.f, ss = 0.f, mn = INFINITY, mx = -INFINITY;
    for (int i = o0; i < o1e; ++i) {
        int2 es = el2[i];
        float4 ea = e4[es.x];
        float ms2 = b2f(nf[(size_t)es.y * 128 + 64 + lane]);
        float t = md2l + ms2 + ea.x*we0 + ea.y*we1 + ea.z*we2v + be2l;
        float h = ea.w * t + bprel;
        s += h; ss += h*h; mn = fminf(mn, h); mx = fmaxf(mx, h);
    }
    int deg = o1e - o0;
    float safe = (float)(deg > 0 ? deg : 1);
    float mean = s / safe;
    float var  = ss / safe - mean * mean;
    float stdv = sqrtf(fmaxf(var, 0.f) + 1e-5f);
    if (deg == 0) { mn = 0.f; mx = 0.f; }
    float avg  = ((const float*)(wsb + B_SUML))[0] * (1.f / NN);
    float s2   = logf(safe + 1.f) / avg;           // o2 = s2*o1; o3 = o1 (s2*s3==1)
    short* a2 = (short*)(wsb + B_A2) + (size_t)n * 576;
    a2[ 64 + lane] = f2b(mean);    a2[128 + lane] = f2b(mn);
    a2[192 + lane] = f2b(mx);      a2[256 + lane] = f2b(stdv);
    a2[320 + lane] = f2b(s2*mean); a2[384 + lane] = f2b(s2*mn);
    a2[448 + lane] = f2b(s2*mx);   a2[512 + lane] = f2b(s2*stdv);
}

// ---- G2 (MFMA): out_pre = a2 @ [Wp_m; W1+W3; W2]  (K=576, N=64) ----
__global__ __launch_bounds__(256) void k_g2(unsigned char* __restrict__ wsb)
{
    const short* a2 = (const short*)(wsb + B_A2);
    const short* bf = (const short*)(wsb + B_BG2);
    short* a3 = (short*)(wsb + B_A3);
    int w = threadIdx.x >> 6, lane = threadIdx.x & 63;
    int quad = lane >> 4, l15 = lane & 15;
    int R0 = blockIdx.x * 64 + w * 16;
    const short* arow = a2 + (size_t)(R0 + l15) * 576 + quad * 8;
    f4v acc[4];
    #pragma unroll
    for (int t = 0; t < 4; ++t) acc[t] = (f4v){0.f,0.f,0.f,0.f};
    #pragma unroll 3
    for (int sK = 0; sK < 18; ++sK) {
        s8v a = *(const s8v*)(arow + sK * 32);
        #pragma unroll
        for (int t = 0; t < 4; ++t) {
            s8v b = *(const s8v*)(bf + ((size_t)(t*18 + sK)*64 + lane)*8);
            acc[t] = __builtin_amdgcn_mfma_f32_16x16x32_bf16(a, b, acc[t], 0, 0, 0);
        }
    }
    #pragma unroll
    for (int t = 0; t < 4; ++t)
        #pragma unroll
        for (int r = 0; r < 4; ++r) {
            int row = R0 + quad*4 + r;
            if (row < NN) a3[(size_t)row*64 + t*16 + l15] = f2b(acc[t][r]);
        }
}

// ---- G3 (MFMA) + GRU epilogue ----
__global__ __launch_bounds__(256) void k_g3gru(const float* __restrict__ x,
    const float* __restrict__ bhh, unsigned char* __restrict__ wsb,
    float* __restrict__ out)
{
    const short* a3 = (const short*)(wsb + B_A3);
    const short* bf = (const short*)(wsb + B_BG3);
    const short* gh = (const short*)(wsb + B_GH);
    const float* b3 = (const float*)(wsb + B_B3);
    int w = threadIdx.x >> 6, lane = threadIdx.x & 63;
    int quad = lane >> 4, l15 = lane & 15;
    int R0 = blockIdx.x * 64 + w * 16;
    const short* arow = a3 + (size_t)(R0 + l15) * 64 + quad * 8;
    s8v a0 = *(const s8v*)(arow);
    s8v a1 = *(const s8v*)(arow + 32);
    f4v acc[12];
    #pragma unroll
    for (int t = 0; t < 12; ++t) acc[t] = (f4v){0.f,0.f,0.f,0.f};
    #pragma unroll
    for (int t = 0; t < 12; ++t) {
        s8v b0 = *(const s8v*)(bf + ((size_t)(t*2+0)*64 + lane)*8);
        s8v b1 = *(const s8v*)(bf + ((size_t)(t*2+1)*64 + lane)*8);
        acc[t] = __builtin_amdgcn_mfma_f32_16x16x32_bf16(a0, b0, acc[t], 0, 0, 0);
        acc[t] = __builtin_amdgcn_mfma_f32_16x16x32_bf16(a1, b1, acc[t], 0, 0, 0);
    }
    #pragma unroll
    for (int t = 0; t < 4; ++t) {
        #pragma unroll
        for (int r = 0; r < 4; ++r) {
            int row = R0 + quad*4 + r;
            if (row >= NN) continue;
            int c = t*16 + l15;
            float ir  = acc[t][r]   + b3[c];
            float iz  = acc[t+4][r] + b3[64 + c];
            float inn = acc[t+8][r] + b3[128 + c];
            const short* g = gh + (size_t)row * 192;
            float hr = b2f(g[c])       + bhh[c];
            float hz = b2f(g[64 + c])  + bhh[64 + c];
            float hn = b2f(g[128 + c]) + bhh[128 + c];
            float rr = 1.f / (1.f + expf(-(ir + hr)));
            float zz = 1.f / (1.f + expf(-(iz + hz)));
            float nn = tanhf(inn + rr * hn);
            out[(size_t)row*64 + c] = (1.f - zz)*nn + zz*x[(size_t)row*64 + c];
        }
    }
}

extern "C" void kernel_launch(void* const* d_in, const int* in_sizes, int n_in,
                              void* d_out, int out_size, void* d_ws, size_t ws_size,
                              hipStream_t stream)
{
    const float* x     = (const float*)d_in[0];
    const float* eattr = (const float*)d_in[1];
    const float* dh    = (const float*)d_in[2];
    const float* W     = (const float*)d_in[3];
    const float* We    = (const float*)d_in[4];
    const float* be    = (const float*)d_in[5];
    const float* Wpre  = (const float*)d_in[6];
    const float* bpre  = (const float*)d_in[7];
    const float* Wpost = (const float*)d_in[8];
    const float* bpost = (const float*)d_in[9];
    const float* Wih   = (const float*)d_in[10];
    const float* bih   = (const float*)d_in[11];
    const float* Whh   = (const float*)d_in[12];
    const float* bhh   = (const float*)d_in[13];
    const int*   eidx  = (const int*)d_in[14];
    unsigned char* wsb = (unsigned char*)d_ws;
    float* out = (float*)d_out;
    const int* srcA = eidx;
    const int* dstA = eidx + NE;
    int* cnt  = (int*)(wsb + B_CNT);
    int* offs = (int*)(wsb + B_OFFS);
    int* cur  = (int*)(wsb + B_CUR);
    int2* el2 = (int2*)(wsb + B_EL2);
    int* part = (int*)(wsb + B_PART);

    hipMemsetAsync(wsb + B_SUML, 0, 4, stream);
    hipMemsetAsync(cnt, 0, NN * sizeof(int), stream);

    k0_weights<<<38, 256, 0, stream>>>(W, Wpre, We, be, bpost, Wpost, Wih, bih, Whh, wsb);
    k_avglog  <<<(NN + 255)/256, 256, 0, stream>>>(dh, (float*)(wsb + B_SUML));
    k_count   <<<NE/256, 256, 0, stream>>>(dstA, cnt);
    k_scanA   <<<SCAN_B, 256, 0, stream>>>(cnt, cur, part);   // cur = local scans (temp)
    k_scanB   <<<1, 256, 0, stream>>>(part, offs);
    k_scanC   <<<SCAN_B, 256, 0, stream>>>(part, cur, offs, cur);
    k_scatter <<<NE/256, 256, 0, stream>>>(srcA, dstA, cur, el2);
    k_xcast   <<<1563, 256, 0, stream>>>(x, wsb);
    k_g1      <<<NNP/64, 256, 0, stream>>>(wsb);
    k_agg     <<<NN/4, 256, 0, stream>>>(eattr, bpre, wsb);
    k_g2      <<<NNP/64, 256, 0, stream>>>(wsb);
    k_g3gru   <<<NNP/64, 256, 0, stream>>>(x, bhh, wsb, out);
}

// Round 5
// 319.257 us; speedup vs baseline: 2.7663x; 1.1524x over previous
//
#include <hip/hip_runtime.h>
#include <math.h>

#define NN  50000
#define NNP 50048
#define NE  800000

// ---- workspace byte offsets ----
#define B_BG1   0u          // g1 B frags: 24 tiles x 2 ksteps x 64 lanes x 8 bf16 = 49152 B
#define B_BG2   49152u      // g2 B frags: 4 x 18 x 512 bf16 = 73728 B
#define B_BG3   122880u     // g3 B frags: 12 x 2 x 512 bf16 = 24576 B
#define B_WE2   147456u     // 3x64 f32
#define B_BE2   148224u     // 64 f32
#define B_B3    148480u     // 192 f32 (bpost@Wih + bih)
#define B_SUML  149248u     // 1 f32
#define B_XB    149504u     // x bf16: NNP*64
#define B_NF    6555648u    // [md2|ms2] bf16: NNP*128
#define B_GH    19367936u   // gh bf16: NNP*192
#define B_A2    38586368u   // [m|o1|s2*o1] bf16: NNP*576
#define B_A3    96241664u   // out_pre bf16: NNP*64
#define B_CNT   102647808u  // NN int
#define B_OFFS  102847808u  // NN+1 int
#define B_CUR   103047936u  // NN int (also holds per-block local scans mid-pipeline)
#define B_EL2   103247936u  // NE int2 (e, src)
#define B_PART  109647936u  // 196 int block partials
// end ~109.65 MB

#define SCAN_B  196         // 196*256 = 50176 >= NN

typedef __attribute__((ext_vector_type(8))) short s8v;
typedef __attribute__((ext_vector_type(4))) float f4v;

__device__ inline short f2b(float f){
    union { float f; unsigned u; } v; v.f = f;
    unsigned r = v.u + 0x7fffu + ((v.u >> 16) & 1u);
    return (short)(r >> 16);
}
__device__ inline float b2f(short b){
    union { unsigned u; float f; } v; v.u = ((unsigned)(unsigned short)b) << 16;
    return v.f;
}

// ---- k0: fold + pack all B matrices into MFMA fragment order (bf16) ----
__global__ void k0_weights(const float* __restrict__ W, const float* __restrict__ Wpre,
                           const float* __restrict__ We, const float* __restrict__ be,
                           const float* __restrict__ bpost, const float* __restrict__ Wpost,
                           const float* __restrict__ Wih, const float* __restrict__ bih,
                           const float* __restrict__ Whh, unsigned char* __restrict__ wsb)
{
    int idx = blockIdx.x * 256 + threadIdx.x;
    if (idx < 3072) {                       // bg1: B = [W | U1 | U2 | Whh] (64 x 384)
        short* dst = (short*)(wsb + B_BG1);
        int lane = idx & 63, ts = idx >> 6;          // ts = t*2+s, t=0..23
        int t = ts >> 1, s = ts & 1;
        int quad = lane >> 4, l15 = lane & 15, n = t*16 + l15;
        for (int j = 0; j < 8; ++j) {
            int k = s*32 + quad*8 + j;
            float v;
            if (n < 64)       v = W[k*64 + n];
            else if (n < 128) { v = 0.f; for (int c = 0; c < 64; ++c) v += W[k*64+c]*Wpre[c*64 + (n-64)]; }
            else if (n < 192) { v = 0.f; for (int c = 0; c < 64; ++c) v += W[k*64+c]*Wpre[4096 + c*64 + (n-128)]; }
            else              v = Whh[k*192 + (n-192)];
            dst[((size_t)ts*64 + lane)*8 + j] = f2b(v);
        }
    } else if (idx < 3072 + 4608) {         // bg2: B = [Wp_m; W1+W3; W2] (576 x 64)
        int id = idx - 3072;
        short* dst = (short*)(wsb + B_BG2);
        int lane = id & 63, ts = id >> 6;            // ts = t*18+s, t=0..3, s=0..17
        int quad = lane >> 4, l15 = lane & 15;
        int t = ts / 18, s = ts % 18;
        int n = t*16 + l15;
        for (int j = 0; j < 8; ++j) {
            int k = s*32 + quad*8 + j;
            float v;
            if (k < 64)       v = Wpost[k*64 + n];
            else if (k < 320) v = Wpost[k*64 + n] + Wpost[(k+512)*64 + n];  // o3==o1 fold
            else              v = Wpost[k*64 + n];
            dst[((size_t)ts*64 + lane)*8 + j] = f2b(v);
        }
    } else if (idx < 9216) {                // bg3: B = Wih (64 x 192)
        int id = idx - 7680;
        short* dst = (short*)(wsb + B_BG3);
        int lane = id & 63, ts = id >> 6;            // ts = t*2+s, t=0..11
        int t = ts >> 1, s = ts & 1;
        int quad = lane >> 4, l15 = lane & 15, n = t*16 + l15;
        for (int j = 0; j < 8; ++j) {
            int k = s*32 + quad*8 + j;
            dst[((size_t)ts*64 + lane)*8 + j] = f2b(Wih[k*192 + n]);
        }
    } else if (idx < 9408) {                // We2 = We @ Wpre3 (3 x 64)
        int t2 = idx - 9216; int kk = t2 >> 6, j = t2 & 63;
        float v = 0.f;
        for (int c = 0; c < 64; ++c) v += We[kk*64 + c] * Wpre[(128+c)*64 + j];
        ((float*)(wsb + B_WE2))[t2] = v;
    } else if (idx < 9472) {                // be2 = be @ Wpre3
        int j = idx - 9408;
        float v = 0.f;
        for (int c = 0; c < 64; ++c) v += be[c] * Wpre[(128+c)*64 + j];
        ((float*)(wsb + B_BE2))[j] = v;
    } else if (idx < 9664) {                // b3 = bpost@Wih + bih
        int j = idx - 9472;
        float v = bih[j];
        for (int k = 0; k < 64; ++k) v += bpost[k] * Wih[k*192 + j];
        ((float*)(wsb + B_B3))[j] = v;
    }
}

__global__ void k_avglog(const float* __restrict__ dh, float* __restrict__ sum)
{
    int i = blockIdx.x * 256 + threadIdx.x;
    float v = (i < NN) ? logf(dh[i] + 1.f) : 0.f;
    #pragma unroll
    for (int m = 32; m >= 1; m >>= 1) v += __shfl_xor(v, m, 64);
    __shared__ float s[4];
    if ((threadIdx.x & 63) == 0) s[threadIdx.x >> 6] = v;
    __syncthreads();
    if (threadIdx.x == 0) atomicAdd(sum, s[0] + s[1] + s[2] + s[3]);
}

// ---- x -> bf16 ----
__global__ void k_xcast(const float* __restrict__ x, unsigned char* __restrict__ wsb)
{
    int i = blockIdx.x * 256 + threadIdx.x;
    if ((size_t)i * 8 >= (size_t)NN * 64) return;
    const float4* xp = (const float4*)(x + (size_t)i * 8);
    float4 p0 = xp[0], p1 = xp[1];
    s8v o;
    o[0]=f2b(p0.x); o[1]=f2b(p0.y); o[2]=f2b(p0.z); o[3]=f2b(p0.w);
    o[4]=f2b(p1.x); o[5]=f2b(p1.y); o[6]=f2b(p1.z); o[7]=f2b(p1.w);
    *(s8v*)((short*)(wsb + B_XB) + (size_t)i * 8) = o;
}

// ---- CSR build ----
__global__ void k_count(const int* __restrict__ dstA, int* __restrict__ cnt)
{
    int e = blockIdx.x * 256 + threadIdx.x;
    if (e < NE) atomicAdd(&cnt[dstA[e]], 1);
}

// 3-phase scan
__global__ __launch_bounds__(256) void k_scanA(const int* __restrict__ cnt,
    int* __restrict__ loc, int* __restrict__ part)
{
    __shared__ int sh[256];
    int t = threadIdx.x, i = blockIdx.x * 256 + t;
    int v = (i < NN) ? cnt[i] : 0;
    sh[t] = v; __syncthreads();
    #pragma unroll
    for (int o = 1; o < 256; o <<= 1) {
        int u = (t >= o) ? sh[t - o] : 0;
        __syncthreads();
        sh[t] += u;
        __syncthreads();
    }
    if (i < NN) loc[i] = sh[t] - v;          // block-local exclusive
    if (t == 255) part[blockIdx.x] = sh[255];
}

__global__ __launch_bounds__(256) void k_scanB(int* __restrict__ part,
    int* __restrict__ offs)
{
    __shared__ int sh[256];
    int t = threadIdx.x;
    int v = (t < SCAN_B) ? part[t] : 0;
    sh[t] = v; __syncthreads();
    #pragma unroll
    for (int o = 1; o < 256; o <<= 1) {
        int u = (t >= o) ? sh[t - o] : 0;
        __syncthreads();
        sh[t] += u;
        __syncthreads();
    }
    if (t < SCAN_B) part[t] = sh[t] - v;     // exclusive base per block
    if (t == 255) offs[NN] = sh[255];
}

__global__ __launch_bounds__(256) void k_scanC(const int* __restrict__ part,
    int* __restrict__ loc, int* __restrict__ offs, int* __restrict__ cur)
{
    int i = blockIdx.x * 256 + threadIdx.x;
    if (i < NN) {
        int v = loc[i] + part[blockIdx.x];
        offs[i] = v; cur[i] = v;
    }
}

__global__ void k_scatter(const int* __restrict__ srcA, const int* __restrict__ dstA,
                          int* __restrict__ cur, int2* __restrict__ el2)
{
    int e = blockIdx.x * 256 + threadIdx.x;
    if (e < NE) {
        int p = atomicAdd(&cur[dstA[e]], 1);
        el2[p] = make_int2(e, srcA[e]);
    }
}

// ---- G1 (MFMA): xw = x @ [W|U1|U2|Whh], epilogue -> a2(m), nf(md2|ms2), gh ----
__global__ __launch_bounds__(256) void k_g1(unsigned char* __restrict__ wsb)
{
    const short* xb = (const short*)(wsb + B_XB);
    const short* bf = (const short*)(wsb + B_BG1);
    short* a2 = (short*)(wsb + B_A2);
    short* nf = (short*)(wsb + B_NF);
    short* gh = (short*)(wsb + B_GH);
    int w = threadIdx.x >> 6, lane = threadIdx.x & 63;
    int quad = lane >> 4, l15 = lane & 15;
    int R0 = blockIdx.x * 64 + w * 16;
    const short* arow = xb + (size_t)(R0 + l15) * 64 + quad * 8;
    s8v a0 = *(const s8v*)(arow);
    s8v a1 = *(const s8v*)(arow + 32);
    f4v acc[24];
    #pragma unroll
    for (int t = 0; t < 24; ++t) acc[t] = (f4v){0.f,0.f,0.f,0.f};
    #pragma unroll
    for (int t = 0; t < 24; ++t) {
        s8v b0 = *(const s8v*)(bf + ((size_t)(t*2+0)*64 + lane)*8);
        s8v b1 = *(const s8v*)(bf + ((size_t)(t*2+1)*64 + lane)*8);
        acc[t] = __builtin_amdgcn_mfma_f32_16x16x32_bf16(a0, b0, acc[t], 0, 0, 0);
        acc[t] = __builtin_amdgcn_mfma_f32_16x16x32_bf16(a1, b1, acc[t], 0, 0, 0);
    }
    #pragma unroll
    for (int t = 0; t < 24; ++t) {
        #pragma unroll
        for (int r = 0; r < 4; ++r) {
            int row = R0 + quad*4 + r;
            if (row >= NN) continue;
            short v = f2b(acc[t][r]);
            if (t < 4)       a2[(size_t)row*576 + t*16 + l15] = v;
            else if (t < 12) nf[(size_t)row*128 + (t-4)*16 + l15] = v;
            else             gh[(size_t)row*192 + (t-12)*16 + l15] = v;
        }
    }
}

// ---- aggregation v2: wave-per-node, LDS metadata preload + batched gathers ----
__global__ __launch_bounds__(256) void k_agg(const float* __restrict__ eattr,
    const float* __restrict__ bpre, unsigned char* __restrict__ wsb)
{
    __shared__ float4 sEA[4][64];            // per-wave edge metadata (wave-private)
    __shared__ int    sSRC[4][64];
    int lane = threadIdx.x & 63;
    int w    = threadIdx.x >> 6;
    int n = blockIdx.x * 4 + w;
    const int* offs = (const int*)(wsb + B_OFFS);
    const int2* el2 = (const int2*)(wsb + B_EL2);
    const short* nf = (const short*)(wsb + B_NF);
    const float* we2p = (const float*)(wsb + B_WE2);
    float we0 = we2p[lane], we1 = we2p[64 + lane], we2v = we2p[128 + lane];
    float be2l = ((const float*)(wsb + B_BE2))[lane];
    float bprel = bpre[lane];
    float md2l = b2f(nf[(size_t)n * 128 + lane]);
    int o0 = offs[n], o1e = offs[n + 1];
    const float4* e4 = (const float4*)eattr;
    const short* nfp = nf + 64 + lane;       // ms2 base for this lane
    float s = 0.f, ss = 0.f, mn = INFINITY, mx = -INFINITY;

    for (int base = o0; base < o1e; base += 64) {
        int cnt = o1e - base; if (cnt > 64) cnt = 64;
        if (lane < cnt) {                    // one coalesced el2 load + parallel ea gather
            int2 es = el2[base + lane];
            sSRC[w][lane] = es.y;
            sEA[w][lane]  = e4[es.x];
        }
        // wave-private LDS: no barrier needed (lockstep wave, compiler waits lgkmcnt)
        for (int d0 = 0; d0 < cnt; d0 += 8) {
            short raw[8];
            #pragma unroll
            for (int u = 0; u < 8; ++u) {    // 8 independent gathers in flight
                int d = d0 + u; if (d > cnt - 1) d = cnt - 1;
                raw[u] = nfp[(size_t)sSRC[w][d] * 128];
            }
            #pragma unroll
            for (int u = 0; u < 8; ++u) {
                int d = d0 + u;
                if (d < cnt) {
                    float4 ea = sEA[w][d];
                    float t = md2l + b2f(raw[u]) + ea.x*we0 + ea.y*we1 + ea.z*we2v + be2l;
                    float h = ea.w * t + bprel;
                    s += h; ss = fmaf(h, h, ss); mn = fminf(mn, h); mx = fmaxf(mx, h);
                }
            }
        }
    }

    int deg = o1e - o0;
    float safe = (float)(deg > 0 ? deg : 1);
    float mean = s / safe;
    float var  = ss / safe - mean * mean;
    float stdv = sqrtf(fmaxf(var, 0.f) + 1e-5f);
    if (deg == 0) { mn = 0.f; mx = 0.f; }
    float avg  = ((const float*)(wsb + B_SUML))[0] * (1.f / NN);
    float s2   = logf(safe + 1.f) / avg;     // o2 = s2*o1; o3 = o1 (s2*s3==1)
    short* a2 = (short*)(wsb + B_A2) + (size_t)n * 576;
    a2[ 64 + lane] = f2b(mean);    a2[128 + lane] = f2b(mn);
    a2[192 + lane] = f2b(mx);      a2[256 + lane] = f2b(stdv);
    a2[320 + lane] = f2b(s2*mean); a2[384 + lane] = f2b(s2*mn);
    a2[448 + lane] = f2b(s2*mx);   a2[512 + lane] = f2b(s2*stdv);
}

// ---- G2 (MFMA): out_pre = a2 @ [Wp_m; W1+W3; W2]  (K=576, N=64) ----
__global__ __launch_bounds__(256) void k_g2(unsigned char* __restrict__ wsb)
{
    const short* a2 = (const short*)(wsb + B_A2);
    const short* bf = (const short*)(wsb + B_BG2);
    short* a3 = (short*)(wsb + B_A3);
    int w = threadIdx.x >> 6, lane = threadIdx.x & 63;
    int quad = lane >> 4, l15 = lane & 15;
    int R0 = blockIdx.x * 64 + w * 16;
    const short* arow = a2 + (size_t)(R0 + l15) * 576 + quad * 8;
    f4v acc[4];
    #pragma unroll
    for (int t = 0; t < 4; ++t) acc[t] = (f4v){0.f,0.f,0.f,0.f};
    #pragma unroll 3
    for (int sK = 0; sK < 18; ++sK) {
        s8v a = *(const s8v*)(arow + sK * 32);
        #pragma unroll
        for (int t = 0; t < 4; ++t) {
            s8v b = *(const s8v*)(bf + ((size_t)(t*18 + sK)*64 + lane)*8);
            acc[t] = __builtin_amdgcn_mfma_f32_16x16x32_bf16(a, b, acc[t], 0, 0, 0);
        }
    }
    #pragma unroll
    for (int t = 0; t < 4; ++t)
        #pragma unroll
        for (int r = 0; r < 4; ++r) {
            int row = R0 + quad*4 + r;
            if (row < NN) a3[(size_t)row*64 + t*16 + l15] = f2b(acc[t][r]);
        }
}

// ---- G3 (MFMA) + GRU epilogue ----
__global__ __launch_bounds__(256) void k_g3gru(const float* __restrict__ x,
    const float* __restrict__ bhh, unsigned char* __restrict__ wsb,
    float* __restrict__ out)
{
    const short* a3 = (const short*)(wsb + B_A3);
    const short* bf = (const short*)(wsb + B_BG3);
    const short* gh = (const short*)(wsb + B_GH);
    const float* b3 = (const float*)(wsb + B_B3);
    int w = threadIdx.x >> 6, lane = threadIdx.x & 63;
    int quad = lane >> 4, l15 = lane & 15;
    int R0 = blockIdx.x * 64 + w * 16;
    const short* arow = a3 + (size_t)(R0 + l15) * 64 + quad * 8;
    s8v a0 = *(const s8v*)(arow);
    s8v a1 = *(const s8v*)(arow + 32);
    f4v acc[12];
    #pragma unroll
    for (int t = 0; t < 12; ++t) acc[t] = (f4v){0.f,0.f,0.f,0.f};
    #pragma unroll
    for (int t = 0; t < 12; ++t) {
        s8v b0 = *(const s8v*)(bf + ((size_t)(t*2+0)*64 + lane)*8);
        s8v b1 = *(const s8v*)(bf + ((size_t)(t*2+1)*64 + lane)*8);
        acc[t] = __builtin_amdgcn_mfma_f32_16x16x32_bf16(a0, b0, acc[t], 0, 0, 0);
        acc[t] = __builtin_amdgcn_mfma_f32_16x16x32_bf16(a1, b1, acc[t], 0, 0, 0);
    }
    #pragma unroll
    for (int t = 0; t < 4; ++t) {
        #pragma unroll
        for (int r = 0; r < 4; ++r) {
            int row = R0 + quad*4 + r;
            if (row >= NN) continue;
            int c = t*16 + l15;
            float ir  = acc[t][r]   + b3[c];
            float iz  = acc[t+4][r] + b3[64 + c];
            float inn = acc[t+8][r] + b3[128 + c];
            const short* g = gh + (size_t)row * 192;
            float hr = b2f(g[c])       + bhh[c];
            float hz = b2f(g[64 + c])  + bhh[64 + c];
            float hn = b2f(g[128 + c]) + bhh[128 + c];
            float rr = 1.f / (1.f + expf(-(ir + hr)));
            float zz = 1.f / (1.f + expf(-(iz + hz)));
            float nn = tanhf(inn + rr * hn);
            out[(size_t)row*64 + c] = (1.f - zz)*nn + zz*x[(size_t)row*64 + c];
        }
    }
}

extern "C" void kernel_launch(void* const* d_in, const int* in_sizes, int n_in,
                              void* d_out, int out_size, void* d_ws, size_t ws_size,
                              hipStream_t stream)
{
    const float* x     = (const float*)d_in[0];
    const float* eattr = (const float*)d_in[1];
    const float* dh    = (const float*)d_in[2];
    const float* W     = (const float*)d_in[3];
    const float* We    = (const float*)d_in[4];
    const float* be    = (const float*)d_in[5];
    const float* Wpre  = (const float*)d_in[6];
    const float* bpre  = (const float*)d_in[7];
    const float* Wpost = (const float*)d_in[8];
    const float* bpost = (const float*)d_in[9];
    const float* Wih   = (const float*)d_in[10];
    const float* bih   = (const float*)d_in[11];
    const float* Whh   = (const float*)d_in[12];
    const float* bhh   = (const float*)d_in[13];
    const int*   eidx  = (const int*)d_in[14];
    unsigned char* wsb = (unsigned char*)d_ws;
    float* out = (float*)d_out;
    const int* srcA = eidx;
    const int* dstA = eidx + NE;
    int* cnt  = (int*)(wsb + B_CNT);
    int* offs = (int*)(wsb + B_OFFS);
    int* cur  = (int*)(wsb + B_CUR);
    int2* el2 = (int2*)(wsb + B_EL2);
    int* part = (int*)(wsb + B_PART);

    hipMemsetAsync(wsb + B_SUML, 0, 4, stream);
    hipMemsetAsync(cnt, 0, NN * sizeof(int), stream);

    k0_weights<<<38, 256, 0, stream>>>(W, Wpre, We, be, bpost, Wpost, Wih, bih, Whh, wsb);
    k_avglog  <<<(NN + 255)/256, 256, 0, stream>>>(dh, (float*)(wsb + B_SUML));
    k_count   <<<NE/256, 256, 0, stream>>>(dstA, cnt);
    k_scanA   <<<SCAN_B, 256, 0, stream>>>(cnt, cur, part);
    k_scanB   <<<1, 256, 0, stream>>>(part, offs);
    k_scanC   <<<SCAN_B, 256, 0, stream>>>(part, cur, offs, cur);
    k_scatter <<<NE/256, 256, 0, stream>>>(srcA, dstA, cur, el2);
    k_xcast   <<<1563, 256, 0, stream>>>(x, wsb);
    k_g1      <<<NNP/64, 256, 0, stream>>>(wsb);
    k_agg     <<<NN/4, 256, 0, stream>>>(eattr, bpre, wsb);
    k_g2      <<<NNP/64, 256, 0, stream>>>(wsb);
    k_g3gru   <<<NNP/64, 256, 0, stream>>>(x, bhh, wsb, out);
}

// Round 6
// 296.600 us; speedup vs baseline: 2.9776x; 1.0764x over previous
//
#include <hip/hip_runtime.h>
#include <math.h>

#define NN  50000
#define NNP 50048
#define NE  800000

// ---- workspace byte offsets ----
#define B_BG1   0u          // g1 B frags: 24 tiles x 2 ks x 512 bf16 = 49152 B
#define B_BG2A  49152u      // g2 grp1 frags: 4 x 10 x 512 bf16 = 40960 B
#define B_BG2B  90112u      // g2 grp2 frags: 4 x 8 x 512 bf16 = 32768 B
#define B_BG3   122880u     // g3 frags: 12 x 2 x 512 bf16 = 24576 B
#define B_WE2   147456u     // 3x64 f32
#define B_BE2   148224u     // 64 f32
#define B_B3    148480u     // 192 f32 (bpost@Wih + bih)
#define B_SUML  149248u     // 1 f32
#define B_XB    149504u     // x bf16: NNP*64
#define B_NF    6555648u    // [md2|ms2] bf16: NNP*128 (256 B/row)
#define B_GH    19367936u   // gh bf16: NNP*192
#define B_A2    38586368u   // [m|o1] bf16: NNP*320 (640 B/row)
#define B_S2F   70617088u   // NN f32: s2 = log(deg+1)/avg
#define B_CNT   70817280u   // NN int
#define B_OFFS  71017280u   // NN+1 int
#define B_CUR   71217408u   // NN int
#define B_EL2   71417856u   // NE int2 (e, src)
#define B_PART  77817856u   // 196 int block partials
// end ~77.8 MB

#define SCAN_B  196         // 196*256 = 50176 >= NN

typedef __attribute__((ext_vector_type(8))) short s8v;
typedef __attribute__((ext_vector_type(4))) float f4v;

__device__ inline short f2b(float f){
    union { float f; unsigned u; } v; v.f = f;
    unsigned r = v.u + 0x7fffu + ((v.u >> 16) & 1u);
    return (short)(r >> 16);
}
__device__ inline float b2f(short b){
    union { unsigned u; float f; } v; v.u = ((unsigned)(unsigned short)b) << 16;
    return v.f;
}

// ---- k_prep: weight fold/pack + xcast + degree count + avglog, one launch ----
// blocks 0..37: k0 pack; 38..1600: xcast; 1601..1796: avglog; ALL: count
__global__ __launch_bounds__(256) void k_prep(const float* __restrict__ x,
    const float* __restrict__ dh, const int* __restrict__ dstA,
    const float* __restrict__ W, const float* __restrict__ Wpre,
    const float* __restrict__ We, const float* __restrict__ be,
    const float* __restrict__ bpost, const float* __restrict__ Wpost,
    const float* __restrict__ Wih, const float* __restrict__ bih,
    const float* __restrict__ Whh, int* __restrict__ cnt,
    unsigned char* __restrict__ wsb)
{
    __shared__ float sred[4];
    int b = blockIdx.x, t = threadIdx.x;
    // job: degree count (all blocks; 3125*256 == NE exactly)
    atomicAdd(&cnt[dstA[b * 256 + t]], 1);

    if (b < 38) {                            // job: weight fold + MFMA-frag pack
        int idx = b * 256 + t;
        if (idx < 3072) {                    // bg1: [W | U1 | U2 | Whh] (64 x 384)
            short* dst = (short*)(wsb + B_BG1);
            int lane = idx & 63, ts = idx >> 6;
            int tt = ts >> 1, s = ts & 1;
            int quad = lane >> 4, l15 = lane & 15, n = tt*16 + l15;
            for (int j = 0; j < 8; ++j) {
                int k = s*32 + quad*8 + j;
                float v;
                if (n < 64)       v = W[k*64 + n];
                else if (n < 128) { v = 0.f; for (int c = 0; c < 64; ++c) v += W[k*64+c]*Wpre[c*64 + (n-64)]; }
                else if (n < 192) { v = 0.f; for (int c = 0; c < 64; ++c) v += W[k*64+c]*Wpre[4096 + c*64 + (n-128)]; }
                else              v = Whh[k*192 + (n-192)];
                dst[((size_t)ts*64 + lane)*8 + j] = f2b(v);
            }
        } else if (idx < 5632) {             // bg2a: [Wp_m; W1+W3] (320 x 64)
            int id = idx - 3072;
            short* dst = (short*)(wsb + B_BG2A);
            int lane = id & 63, ts = id >> 6;            // ts = t*10+s
            int quad = lane >> 4, l15 = lane & 15;
            int tt = ts / 10, s = ts % 10;
            int n = tt*16 + l15;
            for (int j = 0; j < 8; ++j) {
                int k = s*32 + quad*8 + j;               // 0..319
                float v = Wpost[k*64 + n];
                if (k >= 64) v += Wpost[(k + 512)*64 + n];   // o3==o1 fold
                dst[((size_t)ts*64 + lane)*8 + j] = f2b(v);
            }
        } else if (idx < 7680) {             // bg2b: W2 (256 x 64)
            int id = idx - 5632;
            short* dst = (short*)(wsb + B_BG2B);
            int lane = id & 63, ts = id >> 6;            // ts = t*8+s
            int quad = lane >> 4, l15 = lane & 15;
            int tt = ts / 8, s = ts % 8;
            int n = tt*16 + l15;
            for (int j = 0; j < 8; ++j) {
                int k = s*32 + quad*8 + j;               // 0..255
                dst[((size_t)ts*64 + lane)*8 + j] = f2b(Wpost[(320 + k)*64 + n]);
            }
        } else if (idx < 9216) {             // bg3: Wih (64 x 192)
            int id = idx - 7680;
            short* dst = (short*)(wsb + B_BG3);
            int lane = id & 63, ts = id >> 6;            // ts = t*2+s
            int tt = ts >> 1, s = ts & 1;
            int quad = lane >> 4, l15 = lane & 15, n = tt*16 + l15;
            for (int j = 0; j < 8; ++j) {
                int k = s*32 + quad*8 + j;
                dst[((size_t)ts*64 + lane)*8 + j] = f2b(Wih[k*192 + n]);
            }
        } else if (idx < 9408) {             // We2 = We @ Wpre3 (3 x 64)
            int t2 = idx - 9216; int kk = t2 >> 6, j = t2 & 63;
            float v = 0.f;
            for (int c = 0; c < 64; ++c) v += We[kk*64 + c] * Wpre[(128+c)*64 + j];
            ((float*)(wsb + B_WE2))[t2] = v;
        } else if (idx < 9472) {             // be2 = be @ Wpre3
            int j = idx - 9408;
            float v = 0.f;
            for (int c = 0; c < 64; ++c) v += be[c] * Wpre[(128+c)*64 + j];
            ((float*)(wsb + B_BE2))[j] = v;
        } else if (idx < 9664) {             // b3 = bpost@Wih + bih
            int j = idx - 9472;
            float v = bih[j];
            for (int k = 0; k < 64; ++k) v += bpost[k] * Wih[k*192 + j];
            ((float*)(wsb + B_B3))[j] = v;
        }
    } else if (b < 1601) {                   // job: x -> bf16
        int i = (b - 38) * 256 + t;
        if (i < 400000) {
            const float4* xp = (const float4*)(x + (size_t)i * 8);
            float4 p0 = xp[0], p1 = xp[1];
            s8v o;
            o[0]=f2b(p0.x); o[1]=f2b(p0.y); o[2]=f2b(p0.z); o[3]=f2b(p0.w);
            o[4]=f2b(p1.x); o[5]=f2b(p1.y); o[6]=f2b(p1.z); o[7]=f2b(p1.w);
            *(s8v*)((short*)(wsb + B_XB) + (size_t)i * 8) = o;
        }
    } else if (b < 1797) {                   // job: sum log(dh+1)
        int i = (b - 1601) * 256 + t;
        float v = (i < NN) ? logf(dh[i] + 1.f) : 0.f;
        #pragma unroll
        for (int m = 32; m >= 1; m >>= 1) v += __shfl_xor(v, m, 64);
        if ((t & 63) == 0) sred[t >> 6] = v;
        __syncthreads();
        if (t == 0) atomicAdd((float*)(wsb + B_SUML), sred[0]+sred[1]+sred[2]+sred[3]);
    }
}

// 3-phase scan
__global__ __launch_bounds__(256) void k_scanA(const int* __restrict__ cnt,
    int* __restrict__ loc, int* __restrict__ part)
{
    __shared__ int sh[256];
    int t = threadIdx.x, i = blockIdx.x * 256 + t;
    int v = (i < NN) ? cnt[i] : 0;
    sh[t] = v; __syncthreads();
    #pragma unroll
    for (int o = 1; o < 256; o <<= 1) {
        int u = (t >= o) ? sh[t - o] : 0;
        __syncthreads();
        sh[t] += u;
        __syncthreads();
    }
    if (i < NN) loc[i] = sh[t] - v;
    if (t == 255) part[blockIdx.x] = sh[255];
}

__global__ __launch_bounds__(256) void k_scanB(int* __restrict__ part,
    int* __restrict__ offs)
{
    __shared__ int sh[256];
    int t = threadIdx.x;
    int v = (t < SCAN_B) ? part[t] : 0;
    sh[t] = v; __syncthreads();
    #pragma unroll
    for (int o = 1; o < 256; o <<= 1) {
        int u = (t >= o) ? sh[t - o] : 0;
        __syncthreads();
        sh[t] += u;
        __syncthreads();
    }
    if (t < SCAN_B) part[t] = sh[t] - v;
    if (t == 255) offs[NN] = sh[255];
}

__global__ __launch_bounds__(256) void k_scanC(const int* __restrict__ part,
    int* __restrict__ loc, int* __restrict__ offs, int* __restrict__ cur)
{
    int i = blockIdx.x * 256 + threadIdx.x;
    if (i < NN) {
        int v = loc[i] + part[blockIdx.x];
        offs[i] = v; cur[i] = v;
    }
}

__global__ void k_scatter(const int* __restrict__ srcA, const int* __restrict__ dstA,
                          int* __restrict__ cur, int2* __restrict__ el2)
{
    int e = blockIdx.x * 256 + threadIdx.x;
    if (e < NE) {
        int p = atomicAdd(&cur[dstA[e]], 1);
        el2[p] = make_int2(e, srcA[e]);
    }
}

// ---- G1 (MFMA): xw = x @ [W|U1|U2|Whh] -> a2(m), nf(md2|ms2), gh ----
__global__ __launch_bounds__(256) void k_g1(unsigned char* __restrict__ wsb)
{
    const short* xb = (const short*)(wsb + B_XB);
    const short* bf = (const short*)(wsb + B_BG1);
    short* a2 = (short*)(wsb + B_A2);
    short* nf = (short*)(wsb + B_NF);
    short* gh = (short*)(wsb + B_GH);
    int w = threadIdx.x >> 6, lane = threadIdx.x & 63;
    int quad = lane >> 4, l15 = lane & 15;
    int R0 = blockIdx.x * 64 + w * 16;
    const short* arow = xb + (size_t)(R0 + l15) * 64 + quad * 8;
    s8v a0 = *(const s8v*)(arow);
    s8v a1 = *(const s8v*)(arow + 32);
    f4v acc[24];
    #pragma unroll
    for (int t = 0; t < 24; ++t) acc[t] = (f4v){0.f,0.f,0.f,0.f};
    #pragma unroll
    for (int t = 0; t < 24; ++t) {
        s8v b0 = *(const s8v*)(bf + ((size_t)(t*2+0)*64 + lane)*8);
        s8v b1 = *(const s8v*)(bf + ((size_t)(t*2+1)*64 + lane)*8);
        acc[t] = __builtin_amdgcn_mfma_f32_16x16x32_bf16(a0, b0, acc[t], 0, 0, 0);
        acc[t] = __builtin_amdgcn_mfma_f32_16x16x32_bf16(a1, b1, acc[t], 0, 0, 0);
    }
    #pragma unroll
    for (int t = 0; t < 24; ++t) {
        #pragma unroll
        for (int r = 0; r < 4; ++r) {
            int row = R0 + quad*4 + r;
            if (row >= NN) continue;
            short v = f2b(acc[t][r]);
            if (t < 4)       a2[(size_t)row*320 + t*16 + l15] = v;
            else if (t < 12) nf[(size_t)row*128 + (t-4)*16 + l15] = v;
            else             gh[(size_t)row*192 + (t-12)*16 + l15] = v;
        }
    }
}

// ---- aggregation v3: grid-stride wave-per-node; writes o1 bf16 + s2 f32 ----
__global__ __launch_bounds__(256) void k_agg(const float* __restrict__ eattr,
    const float* __restrict__ bpre, unsigned char* __restrict__ wsb)
{
    __shared__ float4 sEA[4][64];            // wave-private
    __shared__ int    sOFF[4][64];           // pre-shifted byte offsets src*256
    int lane = threadIdx.x & 63;
    int w    = threadIdx.x >> 6;
    int wid  = blockIdx.x * 4 + w;           // 8192 waves total
    const int* offs = (const int*)(wsb + B_OFFS);
    const int2* el2 = (const int2*)(wsb + B_EL2);
    const unsigned char* nfb = wsb + B_NF;
    const short* nf = (const short*)(wsb + B_NF);
    const float* we2p = (const float*)(wsb + B_WE2);
    float we0 = we2p[lane], we1 = we2p[64 + lane], we2v = we2p[128 + lane];
    float be2l = ((const float*)(wsb + B_BE2))[lane];
    float bprel = bpre[lane];
    float rcpavg = (float)NN / ((const float*)(wsb + B_SUML))[0];
    const float4* e4 = (const float4*)eattr;
    unsigned laneoff = 128u + 2u * (unsigned)lane;   // ms2 half + channel
    short* a2b = (short*)(wsb + B_A2);
    float* s2f = (float*)(wsb + B_S2F);

    for (int n = wid; n < NN; n += 8192) {
        float md2l = b2f(nf[(size_t)n * 128 + lane]);
        float tbase = md2l + be2l;
        int o0 = offs[n], o1e = offs[n + 1];
        float s = 0.f, ss = 0.f, mn = INFINITY, mx = -INFINITY;
        for (int base = o0; base < o1e; base += 64) {
            int cnt = o1e - base; if (cnt > 64) cnt = 64;
            if (lane < cnt) {
                int2 es = el2[base + lane];
                sOFF[w][lane] = es.y << 8;
                sEA[w][lane]  = e4[es.x];
            }
            for (int d0 = 0; d0 < cnt; d0 += 8) {
                float msv[8];
                #pragma unroll
                for (int u = 0; u < 8; ++u) {   // 8 independent gathers in flight
                    int d = d0 + u; if (d > cnt - 1) d = cnt - 1;
                    unsigned off = (unsigned)sOFF[w][d] + laneoff;
                    msv[u] = b2f(*(const short*)(nfb + off));
                }
                #pragma unroll
                for (int u = 0; u < 8; ++u) {
                    int d = d0 + u;
                    if (d < cnt) {
                        float4 ea = sEA[w][d];
                        float t = tbase + msv[u];
                        t = fmaf(ea.x, we0, t);
                        t = fmaf(ea.y, we1, t);
                        t = fmaf(ea.z, we2v, t);
                        float h = fmaf(ea.w, t, bprel);
                        s += h; ss = fmaf(h, h, ss);
                        mn = fminf(mn, h); mx = fmaxf(mx, h);
                    }
                }
            }
        }
        int deg = o1e - o0;
        float safe = (float)(deg > 0 ? deg : 1);
        float mean = s / safe;
        float var  = ss / safe - mean * mean;
        float stdv = sqrtf(fmaxf(var, 0.f) + 1e-5f);
        if (deg == 0) { mn = 0.f; mx = 0.f; }
        short* a2r = a2b + (size_t)n * 320;
        a2r[ 64 + lane] = f2b(mean); a2r[128 + lane] = f2b(mn);
        a2r[192 + lane] = f2b(mx);   a2r[256 + lane] = f2b(stdv);
        if (lane == 0) s2f[n] = logf(safe + 1.f) * rcpavg;
    }
}

// ---- G2+G3 fused (MFMA): out_pre = [m|o1]@G1 + s2*(o1@W2); LDS transpose; GRU ----
__global__ __launch_bounds__(256) void k_g23(const float* __restrict__ x,
    const float* __restrict__ bhh, unsigned char* __restrict__ wsb,
    float* __restrict__ out)
{
    __shared__ short sm[64 * 72];            // out_pre tile, row stride 72 (16B-aligned rows)
    __shared__ float sS2[64];
    const short* a2  = (const short*)(wsb + B_A2);
    const short* bgA = (const short*)(wsb + B_BG2A);
    const short* bgB = (const short*)(wsb + B_BG2B);
    const short* bg3 = (const short*)(wsb + B_BG3);
    const short* gh  = (const short*)(wsb + B_GH);
    const float* b3  = (const float*)(wsb + B_B3);
    const float* s2f = (const float*)(wsb + B_S2F);
    int w = threadIdx.x >> 6, lane = threadIdx.x & 63;
    int quad = lane >> 4, l15 = lane & 15;
    int R0 = blockIdx.x * 64 + w * 16;

    {   // s2 tile
        int i = threadIdx.x;
        if (i < 64) {
            int row = blockIdx.x * 64 + i;
            sS2[i] = (row < NN) ? s2f[row] : 0.f;
        }
    }

    // ---- G2: two accumulator groups ----
    const short* aBase = a2 + (size_t)(R0 + l15) * 320 + quad * 8;
    f4v acc1[4], acc2[4];
    #pragma unroll
    for (int t = 0; t < 4; ++t) { acc1[t] = (f4v){0.f,0.f,0.f,0.f}; acc2[t] = (f4v){0.f,0.f,0.f,0.f}; }
    #pragma unroll 2
    for (int s = 0; s < 10; ++s) {           // grp1: K=320 over [m|o1]
        s8v a = *(const s8v*)(aBase + s * 32);
        #pragma unroll
        for (int t = 0; t < 4; ++t) {
            s8v b = *(const s8v*)(bgA + ((size_t)(t*10 + s)*64 + lane)*8);
            acc1[t] = __builtin_amdgcn_mfma_f32_16x16x32_bf16(a, b, acc1[t], 0, 0, 0);
        }
    }
    #pragma unroll 2
    for (int s = 0; s < 8; ++s) {            // grp2: K=256 over o1
        s8v a = *(const s8v*)(aBase + 64 + s * 32);
        #pragma unroll
        for (int t = 0; t < 4; ++t) {
            s8v b = *(const s8v*)(bgB + ((size_t)(t*8 + s)*64 + lane)*8);
            acc2[t] = __builtin_amdgcn_mfma_f32_16x16x32_bf16(a, b, acc2[t], 0, 0, 0);
        }
    }
    __syncthreads();                          // sS2 ready (and sm safe to write)
    #pragma unroll
    for (int t = 0; t < 4; ++t)
        #pragma unroll
        for (int r = 0; r < 4; ++r) {
            int lr = w*16 + quad*4 + r;       // local row 0..63
            float v = acc1[t][r] + sS2[lr] * acc2[t][r];
            sm[lr * 72 + t*16 + l15] = f2b(v);
        }
    __syncthreads();

    // ---- G3: A-frags from LDS tile ----
    const short* arow = sm + (w*16 + l15) * 72 + quad * 8;
    s8v a0 = *(const s8v*)(arow);
    s8v a1 = *(const s8v*)(arow + 32);
    f4v acc[12];
    #pragma unroll
    for (int t = 0; t < 12; ++t) acc[t] = (f4v){0.f,0.f,0.f,0.f};
    #pragma unroll
    for (int t = 0; t < 12; ++t) {
        s8v b0 = *(const s8v*)(bg3 + ((size_t)(t*2+0)*64 + lane)*8);
        s8v b1 = *(const s8v*)(bg3 + ((size_t)(t*2+1)*64 + lane)*8);
        acc[t] = __builtin_amdgcn_mfma_f32_16x16x32_bf16(a0, b0, acc[t], 0, 0, 0);
        acc[t] = __builtin_amdgcn_mfma_f32_16x16x32_bf16(a1, b1, acc[t], 0, 0, 0);
    }
    #pragma unroll
    for (int t = 0; t < 4; ++t) {
        #pragma unroll
        for (int r = 0; r < 4; ++r) {
            int row = R0 + quad*4 + r;
            if (row >= NN) continue;
            int c = t*16 + l15;
            float ir  = acc[t][r]   + b3[c];
            float iz  = acc[t+4][r] + b3[64 + c];
            float inn = acc[t+8][r] + b3[128 + c];
            const short* g = gh + (size_t)row * 192;
            float hr = b2f(g[c])       + bhh[c];
            float hz = b2f(g[64 + c])  + bhh[64 + c];
            float hn = b2f(g[128 + c]) + bhh[128 + c];
            float rr = 1.f / (1.f + expf(-(ir + hr)));
            float zz = 1.f / (1.f + expf(-(iz + hz)));
            float nn = tanhf(inn + rr * hn);
            out[(size_t)row*64 + c] = (1.f - zz)*nn + zz*x[(size_t)row*64 + c];
        }
    }
}

extern "C" void kernel_launch(void* const* d_in, const int* in_sizes, int n_in,
                              void* d_out, int out_size, void* d_ws, size_t ws_size,
                              hipStream_t stream)
{
    const float* x     = (const float*)d_in[0];
    const float* eattr = (const float*)d_in[1];
    const float* dh    = (const float*)d_in[2];
    const float* W     = (const float*)d_in[3];
    const float* We    = (const float*)d_in[4];
    const float* be    = (const float*)d_in[5];
    const float* Wpre  = (const float*)d_in[6];
    const float* bpre  = (const float*)d_in[7];
    const float* Wpost = (const float*)d_in[8];
    const float* bpost = (const float*)d_in[9];
    const float* Wih   = (const float*)d_in[10];
    const float* bih   = (const float*)d_in[11];
    const float* Whh   = (const float*)d_in[12];
    const float* bhh   = (const float*)d_in[13];
    const int*   eidx  = (const int*)d_in[14];
    unsigned char* wsb = (unsigned char*)d_ws;
    float* out = (float*)d_out;
    const int* srcA = eidx;
    const int* dstA = eidx + NE;
    int* cnt  = (int*)(wsb + B_CNT);
    int* offs = (int*)(wsb + B_OFFS);
    int* cur  = (int*)(wsb + B_CUR);
    int2* el2 = (int2*)(wsb + B_EL2);
    int* part = (int*)(wsb + B_PART);

    hipMemsetAsync(wsb + B_SUML, 0, 4, stream);
    hipMemsetAsync(cnt, 0, NN * sizeof(int), stream);

    k_prep    <<<3125, 256, 0, stream>>>(x, dh, dstA, W, Wpre, We, be, bpost,
                                         Wpost, Wih, bih, Whh, cnt, wsb);
    k_scanA   <<<SCAN_B, 256, 0, stream>>>(cnt, cur, part);
    k_scanB   <<<1, 256, 0, stream>>>(part, offs);
    k_scanC   <<<SCAN_B, 256, 0, stream>>>(part, cur, offs, cur);
    k_scatter <<<NE/256, 256, 0, stream>>>(srcA, dstA, cur, el2);
    k_g1      <<<NNP/64, 256, 0, stream>>>(wsb);
    k_agg     <<<2048, 256, 0, stream>>>(eattr, bpre, wsb);
    k_g23     <<<NNP/64, 256, 0, stream>>>(x, bhh, wsb, out);
}

// Round 7
// 256.461 us; speedup vs baseline: 3.4437x; 1.1565x over previous
//
#include <hip/hip_runtime.h>
#include <math.h>

#define NN  50000
#define NNP 50048
#define NE  800000

// ---- workspace byte offsets ----
#define B_BG1   0u          // g1 B frags: 24 tiles x 2 ks x 512 bf16 = 49152 B
#define B_BG2A  49152u      // g2 grp1 frags: 4 x 10 x 512 bf16 = 40960 B
#define B_BG2B  90112u      // g2 grp2 frags: 4 x 8 x 512 bf16 = 32768 B
#define B_BG3   122880u     // g3 frags: 12 x 2 x 512 bf16 = 24576 B
#define B_WE2   147456u     // 3x64 f32
#define B_BE2   148224u     // 64 f32
#define B_B3    148480u     // 192 f32 (bpost@Wih + bih)
#define B_SUML  149248u     // 1 f32
#define B_XB    149504u     // x bf16: NNP*64
#define B_NF    6555648u    // [md2|ms2] bf16: NNP*128 (256 B/row)
#define B_GH    19367936u   // gh bf16: NNP*192
#define B_A2    38586368u   // [m | o1-interleaved] bf16: NNP*320 (640 B/row)
#define B_S2F   70617088u   // NN f32: s2 = log(deg+1)/avg
#define B_CNT   70817280u   // NN int
#define B_OFFS  71017280u   // NN+1 int
#define B_RANK  71217408u   // NE int: edge rank within its dst list
#define B_EL2   74417408u   // NE int2 (e, src)
#define B_PART  80817408u   // 196 int block partials
// end ~80.8 MB

#define SCAN_B  196         // 196*256 = 50176 >= NN

typedef __attribute__((ext_vector_type(8))) short s8v;
typedef __attribute__((ext_vector_type(4))) short s4v;
typedef __attribute__((ext_vector_type(4))) float f4v;

__device__ inline short f2b(float f){
    union { float f; unsigned u; } v; v.f = f;
    unsigned r = v.u + 0x7fffu + ((v.u >> 16) & 1u);
    return (short)(r >> 16);
}
__device__ inline float b2f(short b){
    union { unsigned u; float f; } v; v.u = ((unsigned)(unsigned short)b) << 16;
    return v.f;
}

// ---- k_prep: weight fold/pack + xcast + degree count(+rank) + avglog ----
// ALL 3125 blocks: count+rank (3125*256 == NE). blocks 0..37: pack;
// 38..1600: xcast; 1601..1796: avglog.
__global__ __launch_bounds__(256) void k_prep(const float* __restrict__ x,
    const float* __restrict__ dh, const int* __restrict__ dstA,
    const float* __restrict__ W, const float* __restrict__ Wpre,
    const float* __restrict__ We, const float* __restrict__ be,
    const float* __restrict__ bpost, const float* __restrict__ Wpost,
    const float* __restrict__ Wih, const float* __restrict__ bih,
    const float* __restrict__ Whh, int* __restrict__ cnt,
    int* __restrict__ rank, unsigned char* __restrict__ wsb)
{
    __shared__ float sred[4];
    int b = blockIdx.x, t = threadIdx.x;
    {   // degree count + rank (rank = old count, coalesced store)
        int e = b * 256 + t;
        rank[e] = atomicAdd(&cnt[dstA[e]], 1);
    }

    if (b < 38) {                            // job: weight fold + MFMA-frag pack
        int idx = b * 256 + t;
        if (idx < 3072) {                    // bg1: [W | U1 | U2 | Whh] (64 x 384)
            short* dst = (short*)(wsb + B_BG1);
            int lane = idx & 63, ts = idx >> 6;
            int tt = ts >> 1, s = ts & 1;
            int quad = lane >> 4, l15 = lane & 15, n = tt*16 + l15;
            for (int j = 0; j < 8; ++j) {
                int k = s*32 + quad*8 + j;
                float v;
                if (n < 64)       v = W[k*64 + n];
                else if (n < 128) { v = 0.f; for (int c = 0; c < 64; ++c) v += W[k*64+c]*Wpre[c*64 + (n-64)]; }
                else if (n < 192) { v = 0.f; for (int c = 0; c < 64; ++c) v += W[k*64+c]*Wpre[4096 + c*64 + (n-128)]; }
                else              v = Whh[k*192 + (n-192)];
                dst[((size_t)ts*64 + lane)*8 + j] = f2b(v);
            }
        } else if (idx < 5632) {             // bg2a: [Wp_m; W1+W3 interleaved-K] (320 x 64)
            int id = idx - 3072;
            short* dst = (short*)(wsb + B_BG2A);
            int lane = id & 63, ts = id >> 6;            // ts = tt*10+s
            int quad = lane >> 4, l15 = lane & 15;
            int tt = ts / 10, s = ts % 10;
            int n = tt*16 + l15;
            for (int j = 0; j < 8; ++j) {
                int k = s*32 + quad*8 + j;               // 0..319 (a2 K order)
                float v;
                if (k < 64) v = Wpost[k*64 + n];         // m block, unchanged
                else {                                   // o1 interleaved: k=64+ch*4+st
                    int kk = k - 64, ch = kk >> 2, st = kk & 3;
                    int ok = 64 + st*64 + ch;            // original Wpost row
                    v = Wpost[ok*64 + n] + Wpost[(ok + 512)*64 + n];  // o3==o1 fold
                }
                dst[((size_t)ts*64 + lane)*8 + j] = f2b(v);
            }
        } else if (idx < 7680) {             // bg2b: W2 interleaved-K (256 x 64)
            int id = idx - 5632;
            short* dst = (short*)(wsb + B_BG2B);
            int lane = id & 63, ts = id >> 6;            // ts = tt*8+s
            int quad = lane >> 4, l15 = lane & 15;
            int tt = ts / 8, s = ts % 8;
            int n = tt*16 + l15;
            for (int j = 0; j < 8; ++j) {
                int k = s*32 + quad*8 + j;               // 0..255 (interleaved)
                int ch = k >> 2, st = k & 3;
                int ok = 320 + st*64 + ch;
                dst[((size_t)ts*64 + lane)*8 + j] = f2b(Wpost[ok*64 + n]);
            }
        } else if (idx < 9216) {             // bg3: Wih (64 x 192)
            int id = idx - 7680;
            short* dst = (short*)(wsb + B_BG3);
            int lane = id & 63, ts = id >> 6;            // ts = tt*2+s
            int tt = ts >> 1, s = ts & 1;
            int quad = lane >> 4, l15 = lane & 15, n = tt*16 + l15;
            for (int j = 0; j < 8; ++j) {
                int k = s*32 + quad*8 + j;
                dst[((size_t)ts*64 + lane)*8 + j] = f2b(Wih[k*192 + n]);
            }
        } else if (idx < 9408) {             // We2 = We @ Wpre3 (3 x 64)
            int t2 = idx - 9216; int kk = t2 >> 6, j = t2 & 63;
            float v = 0.f;
            for (int c = 0; c < 64; ++c) v += We[kk*64 + c] * Wpre[(128+c)*64 + j];
            ((float*)(wsb + B_WE2))[t2] = v;
        } else if (idx < 9472) {             // be2 = be @ Wpre3
            int j = idx - 9408;
            float v = 0.f;
            for (int c = 0; c < 64; ++c) v += be[c] * Wpre[(128+c)*64 + j];
            ((float*)(wsb + B_BE2))[j] = v;
        } else if (idx < 9664) {             // b3 = bpost@Wih + bih
            int j = idx - 9472;
            float v = bih[j];
            for (int k = 0; k < 64; ++k) v += bpost[k] * Wih[k*192 + j];
            ((float*)(wsb + B_B3))[j] = v;
        }
    } else if (b < 1601) {                   // job: x -> bf16
        int i = (b - 38) * 256 + t;
        if (i < 400000) {
            const float4* xp = (const float4*)(x + (size_t)i * 8);
            float4 p0 = xp[0], p1 = xp[1];
            s8v o;
            o[0]=f2b(p0.x); o[1]=f2b(p0.y); o[2]=f2b(p0.z); o[3]=f2b(p0.w);
            o[4]=f2b(p1.x); o[5]=f2b(p1.y); o[6]=f2b(p1.z); o[7]=f2b(p1.w);
            *(s8v*)((short*)(wsb + B_XB) + (size_t)i * 8) = o;
        }
    } else if (b < 1797) {                   // job: sum log(dh+1)
        int i = (b - 1601) * 256 + t;
        float v = (i < NN) ? logf(dh[i] + 1.f) : 0.f;
        #pragma unroll
        for (int m = 32; m >= 1; m >>= 1) v += __shfl_xor(v, m, 64);
        if ((t & 63) == 0) sred[t >> 6] = v;
        __syncthreads();
        if (t == 0) atomicAdd((float*)(wsb + B_SUML), sred[0]+sred[1]+sred[2]+sred[3]);
    }
}

// ---- scan phase A: block-local exclusive prefix into offs, total into part ----
__global__ __launch_bounds__(256) void k_scanA(const int* __restrict__ cnt,
    int* __restrict__ offs, int* __restrict__ part)
{
    __shared__ int sh[256];
    int t = threadIdx.x, i = blockIdx.x * 256 + t;
    int v = (i < NN) ? cnt[i] : 0;
    sh[t] = v; __syncthreads();
    #pragma unroll
    for (int o = 1; o < 256; o <<= 1) {
        int u = (t >= o) ? sh[t - o] : 0;
        __syncthreads();
        sh[t] += u;
        __syncthreads();
    }
    if (i < NN) offs[i] = sh[t] - v;
    if (t == 255) part[blockIdx.x] = sh[255];
}

// ---- scan phase C (B folded in): every block scans the 196 partials ----
__global__ __launch_bounds__(256) void k_scanC(const int* __restrict__ part,
    int* __restrict__ offs)
{
    __shared__ int sh[256];
    int b = blockIdx.x, t = threadIdx.x;
    int v = (t < SCAN_B) ? part[t] : 0;
    sh[t] = v; __syncthreads();
    #pragma unroll
    for (int o = 1; o < 256; o <<= 1) {
        int u = (t >= o) ? sh[t - o] : 0;
        __syncthreads();
        sh[t] += u;
        __syncthreads();
    }
    int base = (b == 0) ? 0 : sh[b - 1];     // LDS broadcast, block-uniform
    int i = b * 256 + t;
    if (i < NN) offs[i] += base;
    if (b == 0 && t == 0) offs[NN] = NE;     // total is a compile-time constant
}

// ---- scatter: NO atomics — p = offs[dst] + rank[e]; fire-and-forget stores ----
__global__ __launch_bounds__(256) void k_scatter(const int* __restrict__ srcA,
    const int* __restrict__ dstA, const int* __restrict__ rank,
    const int* __restrict__ offs, int2* __restrict__ el2)
{
    int e = blockIdx.x * 256 + threadIdx.x;  // 3125*256 == NE
    int dst = dstA[e];
    int r   = rank[e];
    int src = srcA[e];
    el2[offs[dst] + r] = make_int2(e, src);
}

// ---- G1 (MFMA): xw = x @ [W|U1|U2|Whh] -> a2(m), nf(md2|ms2), gh ----
__global__ __launch_bounds__(256) void k_g1(unsigned char* __restrict__ wsb)
{
    const short* xb = (const short*)(wsb + B_XB);
    const short* bf = (const short*)(wsb + B_BG1);
    short* a2 = (short*)(wsb + B_A2);
    short* nf = (short*)(wsb + B_NF);
    short* gh = (short*)(wsb + B_GH);
    int w = threadIdx.x >> 6, lane = threadIdx.x & 63;
    int quad = lane >> 4, l15 = lane & 15;
    int R0 = blockIdx.x * 64 + w * 16;
    const short* arow = xb + (size_t)(R0 + l15) * 64 + quad * 8;
    s8v a0 = *(const s8v*)(arow);
    s8v a1 = *(const s8v*)(arow + 32);
    f4v acc[24];
    #pragma unroll
    for (int t = 0; t < 24; ++t) acc[t] = (f4v){0.f,0.f,0.f,0.f};
    #pragma unroll
    for (int t = 0; t < 24; ++t) {
        s8v b0 = *(const s8v*)(bf + ((size_t)(t*2+0)*64 + lane)*8);
        s8v b1 = *(const s8v*)(bf + ((size_t)(t*2+1)*64 + lane)*8);
        acc[t] = __builtin_amdgcn_mfma_f32_16x16x32_bf16(a0, b0, acc[t], 0, 0, 0);
        acc[t] = __builtin_amdgcn_mfma_f32_16x16x32_bf16(a1, b1, acc[t], 0, 0, 0);
    }
    #pragma unroll
    for (int t = 0; t < 24; ++t) {
        #pragma unroll
        for (int r = 0; r < 4; ++r) {
            int row = R0 + quad*4 + r;
            if (row >= NN) continue;
            short v = f2b(acc[t][r]);
            if (t < 4)       a2[(size_t)row*320 + t*16 + l15] = v;
            else if (t < 12) nf[(size_t)row*128 + (t-4)*16 + l15] = v;
            else             gh[(size_t)row*192 + (t-12)*16 + l15] = v;
        }
    }
}

// ---- aggregation: grid-stride wave-per-node; o1 interleaved bf16x4 store ----
__global__ __launch_bounds__(256) void k_agg(const float* __restrict__ eattr,
    const float* __restrict__ bpre, unsigned char* __restrict__ wsb)
{
    __shared__ float4 sEA[4][64];            // wave-private
    __shared__ int    sOFF[4][64];           // pre-shifted byte offsets src*256
    int lane = threadIdx.x & 63;
    int w    = threadIdx.x >> 6;
    int wid  = blockIdx.x * 4 + w;           // 8192 waves total
    const int* offs = (const int*)(wsb + B_OFFS);
    const int2* el2 = (const int2*)(wsb + B_EL2);
    const unsigned char* nfb = wsb + B_NF;
    const short* nf = (const short*)(wsb + B_NF);
    const float* we2p = (const float*)(wsb + B_WE2);
    float we0 = we2p[lane], we1 = we2p[64 + lane], we2v = we2p[128 + lane];
    float be2l = ((const float*)(wsb + B_BE2))[lane];
    float bprel = bpre[lane];
    float rcpavg = (float)NN / ((const float*)(wsb + B_SUML))[0];
    const float4* e4 = (const float4*)eattr;
    unsigned laneoff = 128u + 2u * (unsigned)lane;   // ms2 half + channel
    short* a2b = (short*)(wsb + B_A2);
    float* s2f = (float*)(wsb + B_S2F);

    for (int n = wid; n < NN; n += 8192) {
        float md2l = b2f(nf[(size_t)n * 128 + lane]);
        float tbase = md2l + be2l;
        int o0 = offs[n], o1e = offs[n + 1];
        float s = 0.f, ss = 0.f, mn = INFINITY, mx = -INFINITY;
        for (int base = o0; base < o1e; base += 64) {
            int cnt = o1e - base; if (cnt > 64) cnt = 64;
            if (lane < cnt) {
                int2 es = el2[base + lane];
                sOFF[w][lane] = es.y << 8;
                sEA[w][lane]  = e4[es.x];
            }
            for (int d0 = 0; d0 < cnt; d0 += 8) {
                float msv[8];
                #pragma unroll
                for (int u = 0; u < 8; ++u) {   // 8 independent gathers in flight
                    int d = d0 + u; if (d > cnt - 1) d = cnt - 1;
                    unsigned off = (unsigned)sOFF[w][d] + laneoff;
                    msv[u] = b2f(*(const short*)(nfb + off));
                }
                #pragma unroll
                for (int u = 0; u < 8; ++u) {
                    int d = d0 + u;
                    if (d < cnt) {
                        float4 ea = sEA[w][d];
                        float t = tbase + msv[u];
                        t = fmaf(ea.x, we0, t);
                        t = fmaf(ea.y, we1, t);
                        t = fmaf(ea.z, we2v, t);
                        float h = fmaf(ea.w, t, bprel);
                        s += h; ss = fmaf(h, h, ss);
                        mn = fminf(mn, h); mx = fmaxf(mx, h);
                    }
                }
            }
        }
        int deg = o1e - o0;
        float safe = (float)(deg > 0 ? deg : 1);
        float mean = s / safe;
        float var  = ss / safe - mean * mean;
        float stdv = sqrtf(fmaxf(var, 0.f) + 1e-5f);
        if (deg == 0) { mn = 0.f; mx = 0.f; }
        s4v o; o[0] = f2b(mean); o[1] = f2b(mn); o[2] = f2b(mx); o[3] = f2b(stdv);
        *(s4v*)(a2b + (size_t)n * 320 + 64 + (lane << 2)) = o;   // one 8B store
        if (lane == 0) s2f[n] = logf(safe + 1.f) * rcpavg;
    }
}

// ---- G2+G3 fused (MFMA): out_pre = [m|o1]@G1 + s2*(o1@W2); LDS transpose; GRU ----
__global__ __launch_bounds__(256) void k_g23(const float* __restrict__ x,
    const float* __restrict__ bhh, unsigned char* __restrict__ wsb,
    float* __restrict__ out)
{
    __shared__ short sm[64 * 72];            // out_pre tile, row stride 72
    __shared__ float sS2[64];
    const short* a2  = (const short*)(wsb + B_A2);
    const short* bgA = (const short*)(wsb + B_BG2A);
    const short* bgB = (const short*)(wsb + B_BG2B);
    const short* bg3 = (const short*)(wsb + B_BG3);
    const short* gh  = (const short*)(wsb + B_GH);
    const float* b3  = (const float*)(wsb + B_B3);
    const float* s2f = (const float*)(wsb + B_S2F);
    int w = threadIdx.x >> 6, lane = threadIdx.x & 63;
    int quad = lane >> 4, l15 = lane & 15;
    int R0 = blockIdx.x * 64 + w * 16;

    {   // s2 tile
        int i = threadIdx.x;
        if (i < 64) {
            int row = blockIdx.x * 64 + i;
            sS2[i] = (row < NN) ? s2f[row] : 0.f;
        }
    }

    // ---- G2: two accumulator groups ----
    const short* aBase = a2 + (size_t)(R0 + l15) * 320 + quad * 8;
    f4v acc1[4], acc2[4];
    #pragma unroll
    for (int t = 0; t < 4; ++t) { acc1[t] = (f4v){0.f,0.f,0.f,0.f}; acc2[t] = (f4v){0.f,0.f,0.f,0.f}; }
    #pragma unroll 2
    for (int s = 0; s < 10; ++s) {           // grp1: K=320 over [m|o1]
        s8v a = *(const s8v*)(aBase + s * 32);
        #pragma unroll
        for (int t = 0; t < 4; ++t) {
            s8v b = *(const s8v*)(bgA + ((size_t)(t*10 + s)*64 + lane)*8);
            acc1[t] = __builtin_amdgcn_mfma_f32_16x16x32_bf16(a, b, acc1[t], 0, 0, 0);
        }
    }
    #pragma unroll 2
    for (int s = 0; s < 8; ++s) {            // grp2: K=256 over o1
        s8v a = *(const s8v*)(aBase + 64 + s * 32);
        #pragma unroll
        for (int t = 0; t < 4; ++t) {
            s8v b = *(const s8v*)(bgB + ((size_t)(t*8 + s)*64 + lane)*8);
            acc2[t] = __builtin_amdgcn_mfma_f32_16x16x32_bf16(a, b, acc2[t], 0, 0, 0);
        }
    }
    __syncthreads();                          // sS2 ready (and sm safe to write)
    #pragma unroll
    for (int t = 0; t < 4; ++t)
        #pragma unroll
        for (int r = 0; r < 4; ++r) {
            int lr = w*16 + quad*4 + r;       // local row 0..63
            float v = acc1[t][r] + sS2[lr] * acc2[t][r];
            sm[lr * 72 + t*16 + l15] = f2b(v);
        }
    __syncthreads();

    // ---- G3: A-frags from LDS tile ----
    const short* arow = sm + (w*16 + l15) * 72 + quad * 8;
    s8v a0 = *(const s8v*)(arow);
    s8v a1 = *(const s8v*)(arow + 32);
    f4v acc[12];
    #pragma unroll
    for (int t = 0; t < 12; ++t) acc[t] = (f4v){0.f,0.f,0.f,0.f};
    #pragma unroll
    for (int t = 0; t < 12; ++t) {
        s8v b0 = *(const s8v*)(bg3 + ((size_t)(t*2+0)*64 + lane)*8);
        s8v b1 = *(const s8v*)(bg3 + ((size_t)(t*2+1)*64 + lane)*8);
        acc[t] = __builtin_amdgcn_mfma_f32_16x16x32_bf16(a0, b0, acc[t], 0, 0, 0);
        acc[t] = __builtin_amdgcn_mfma_f32_16x16x32_bf16(a1, b1, acc[t], 0, 0, 0);
    }
    #pragma unroll
    for (int t = 0; t < 4; ++t) {
        #pragma unroll
        for (int r = 0; r < 4; ++r) {
            int row = R0 + quad*4 + r;
            if (row >= NN) continue;
            int c = t*16 + l15;
            float ir  = acc[t][r]   + b3[c];
            float iz  = acc[t+4][r] + b3[64 + c];
            float inn = acc[t+8][r] + b3[128 + c];
            const short* g = gh + (size_t)row * 192;
            float hr = b2f(g[c])       + bhh[c];
            float hz = b2f(g[64 + c])  + bhh[64 + c];
            float hn = b2f(g[128 + c]) + bhh[128 + c];
            float rr = 1.f / (1.f + expf(-(ir + hr)));
            float zz = 1.f / (1.f + expf(-(iz + hz)));
            float nn = tanhf(inn + rr * hn);
            out[(size_t)row*64 + c] = (1.f - zz)*nn + zz*x[(size_t)row*64 + c];
        }
    }
}

extern "C" void kernel_launch(void* const* d_in, const int* in_sizes, int n_in,
                              void* d_out, int out_size, void* d_ws, size_t ws_size,
                              hipStream_t stream)
{
    const float* x     = (const float*)d_in[0];
    const float* eattr = (const float*)d_in[1];
    const float* dh    = (const float*)d_in[2];
    const float* W     = (const float*)d_in[3];
    const float* We    = (const float*)d_in[4];
    const float* be    = (const float*)d_in[5];
    const float* Wpre  = (const float*)d_in[6];
    const float* bpre  = (const float*)d_in[7];
    const float* Wpost = (const float*)d_in[8];
    const float* bpost = (const float*)d_in[9];
    const float* Wih   = (const float*)d_in[10];
    const float* bih   = (const float*)d_in[11];
    const float* Whh   = (const float*)d_in[12];
    const float* bhh   = (const float*)d_in[13];
    const int*   eidx  = (const int*)d_in[14];
    unsigned char* wsb = (unsigned char*)d_ws;
    float* out = (float*)d_out;
    const int* srcA = eidx;
    const int* dstA = eidx + NE;
    int* cnt  = (int*)(wsb + B_CNT);
    int* offs = (int*)(wsb + B_OFFS);
    int* rank = (int*)(wsb + B_RANK);
    int2* el2 = (int2*)(wsb + B_EL2);
    int* part = (int*)(wsb + B_PART);

    hipMemsetAsync(wsb + B_SUML, 0, 4, stream);
    hipMemsetAsync(cnt, 0, NN * sizeof(int), stream);

    k_prep    <<<3125, 256, 0, stream>>>(x, dh, dstA, W, Wpre, We, be, bpost,
                                         Wpost, Wih, bih, Whh, cnt, rank, wsb);
    k_scanA   <<<SCAN_B, 256, 0, stream>>>(cnt, offs, part);
    k_scanC   <<<SCAN_B, 256, 0, stream>>>(part, offs);
    k_scatter <<<NE/256, 256, 0, stream>>>(srcA, dstA, rank, offs, el2);
    k_g1      <<<NNP/64, 256, 0, stream>>>(wsb);
    k_agg     <<<2048, 256, 0, stream>>>(eattr, bpre, wsb);
    k_g23     <<<NNP/64, 256, 0, stream>>>(x, bhh, wsb, out);
}